// Round 5
// baseline (2044.343 us; speedup 1.0000x reference)
//
#include <hip/hip_runtime.h>

typedef __attribute__((ext_vector_type(8))) short short8;
typedef __attribute__((ext_vector_type(4))) float floatx4;

#define MFMA16(a, b, acc) __builtin_amdgcn_mfma_f32_16x16x32_bf16((a), (b), (acc), 0, 0, 0)

__device__ __forceinline__ float bf2f(unsigned short u) {
  union { float f; unsigned int i; } v; v.i = ((unsigned int)u) << 16; return v.f;
}
__device__ __forceinline__ unsigned short f2bf(float f) {
  union { float f; unsigned int i; } v; v.f = f;
  unsigned int r = (v.i + 0x7fffu + ((v.i >> 16) & 1u)) >> 16;
  return (unsigned short)r;
}
__device__ __forceinline__ float sigm(float x) { return 1.0f / (1.0f + __expf(-x)); }
__device__ __forceinline__ float tanh_f(float x) { return 2.0f * sigm(2.0f * x) - 1.0f; }

// write-through 2B store: no L2 allocation, lands at LLC (coherence point)
__device__ __forceinline__ void llc_store_u16(unsigned short* p, unsigned short v) {
  unsigned int v32 = v;
  asm volatile("global_store_short %0, %1, off sc0 sc1" :: "v"(p), "v"(v32) : "memory");
}

// ---------------- flat single-hop checker barrier ----------------
// Arrival: entry __syncthreads makes each wave drain vmcnt(0) (h stores ack'd
// at the coherence point), then every block's t0 stores flags[bid] = phase.
// Notice: every block's wave0 polls ALL 256 flags directly (lane i polls
// flags[4i..4i+3], wave-AND via __all) -> ONE store-visibility + discovery
// link instead of the 3-hop leader/root/gen chain (R0). Phases monotonic,
// max skew 1 phase; producer stores for step p are globally complete before
// any block passes barrier p (same guarantee as the hierarchical version).
__device__ __forceinline__ void gridbar(unsigned int* bar, unsigned int phase) {
  __syncthreads();                     // per-wave vmcnt(0) drain before s_barrier
  const unsigned int tid = threadIdx.x;
  if (tid == 0)
    __hip_atomic_store(&bar[blockIdx.x], phase, __ATOMIC_RELAXED, __HIP_MEMORY_SCOPE_AGENT);
  asm volatile("" ::: "memory");       // flag store before any polling
  if (tid < 64) {
    const unsigned int base = tid << 2;
    for (;;) {
      unsigned int f0 = __hip_atomic_load(&bar[base + 0], __ATOMIC_RELAXED, __HIP_MEMORY_SCOPE_AGENT);
      unsigned int f1 = __hip_atomic_load(&bar[base + 1], __ATOMIC_RELAXED, __HIP_MEMORY_SCOPE_AGENT);
      unsigned int f2 = __hip_atomic_load(&bar[base + 2], __ATOMIC_RELAXED, __HIP_MEMORY_SCOPE_AGENT);
      unsigned int f3 = __hip_atomic_load(&bar[base + 3], __ATOMIC_RELAXED, __HIP_MEMORY_SCOPE_AGENT);
      unsigned int a = f0 < f1 ? f0 : f1;
      unsigned int c = f2 < f3 ? f2 : f3;
      unsigned int m = a < c ? a : c;
      if (__all((int)(m >= phase))) break;
      __builtin_amdgcn_s_sleep(1);
    }
  }
  asm volatile("" ::: "memory");       // no load hoisting above the poll
  __syncthreads();
}

__global__ void zero_bar(unsigned int* bar) {
  int i = blockIdx.x * 256 + threadIdx.x;
  if (i < 1024) bar[i] = 0u;
}

// ---------------- prep kernels ----------------

// ebf[m=t*64+b][k] = bf16(emb[x[b][t]][k])
__global__ void prep_e(const int* __restrict__ x, const float* __restrict__ emb,
                       unsigned short* __restrict__ ebf) {
  int idx = blockIdx.x * 256 + threadIdx.x;   // [0, 8192*32)
  int koct = idx & 31;
  int m = idx >> 5;
  int t = m >> 6, b = m & 63;
  int tok = x[b * 128 + t];
  const float* src = emb + (size_t)tok * 256 + (size_t)koct * 8;
  short8 v;
#pragma unroll
  for (int j = 0; j < 8; ++j) v[j] = (short)f2bf(src[j]);
  *(short8*)(ebf + (size_t)m * 256 + koct * 8) = v;
}

// Wt[n][k] = bf16(W[k][n]); W is [K][4096]
__global__ void prep_wt(const float* __restrict__ W, unsigned short* __restrict__ Wt, int K) {
  int idx = blockIdx.x * 256 + threadIdx.x;   // [0, 4096*(K/8))
  int n = idx & 4095;
  int koct = idx >> 12;
  short8 v;
#pragma unroll
  for (int j = 0; j < 8; ++j) v[j] = (short)f2bf(W[(size_t)(koct * 8 + j) * 4096 + n]);
  *(short8*)(Wt + (size_t)n * K + koct * 8) = v;
}

__global__ void prep_cvt(const float* __restrict__ s, unsigned short* __restrict__ d) {
  int i = blockIdx.x * 256 + threadIdx.x;
  d[i] = f2bf(s[i]);
}

// ---------------- fused two-layer LSTM (one cooperative dispatch) ----------------
// Block bid owns j-quad = bid*4..bid*4+3 for BOTH layers. Super-step s:
//   layer-1: y1[s] from e[s] + h1 (slab s);  layer-2: out[s-1] from y1[s-1]
//   (= slab s, SAME loads) + h2 (slab s-1). 128 barriers total.
// K-SPLIT x2 -> 512 threads, 8 waves, 2 waves/SIMD (R4-proven). Waves 0-3
// (kg=0) reduce ks 0..15, waves 4-7 (kg=1) ks 16..31; partial gate sums
// combine via an 8 KB LDS buffer + one __syncthreads.
// THIS REV (isolated change vs R4): gridbar flattened 3 hops -> 1 hop.
__global__ __launch_bounds__(512, 2) void lstm_fused(
    const unsigned short* __restrict__ W1t,  // [4096][256]  bf16
    const unsigned short* __restrict__ U1t,  // [4096][1024] bf16
    const unsigned short* __restrict__ W2t,  // [4096][1024] bf16
    const unsigned short* __restrict__ U2t,  // [4096][1024] bf16
    const unsigned short* __restrict__ ebf,  // [8192][256]  bf16
    unsigned short* __restrict__ h1h,        // [129][64][1024], slab 0 prefilled
    unsigned short* __restrict__ h2h,        // [129][64][1024], slab 0 prefilled
    const float* __restrict__ c0_1, const float* __restrict__ c0_2,
    const float* __restrict__ b1,   const float* __restrict__ b2,
    float* __restrict__ outy,                 // [64][128][1024]
    float* __restrict__ hT1, float* __restrict__ cT1,
    float* __restrict__ hT2, float* __restrict__ cT2,
    unsigned int* __restrict__ bar) {
  extern __shared__ __align__(16) unsigned short lds[];   // 112 KB total
  unsigned short* U1l = lds;             // 32 KB
  unsigned short* W2l = lds + 16384;     // 32 KB
  unsigned short* U2l = lds + 32768;     // 32 KB
  unsigned short* W1l = lds + 49152;     // 8 KB (bytes 98304..106496)
  float* red = (float*)(lds + 53248);    // 8 KB: [8][256] f32, transposed (bank-clean)
  const int bid = blockIdx.x, tid = threadIdx.x;
  const int w = tid >> 6, l = tid & 63;
  const int kg = w >> 2;                 // K-group: 0 -> ks 0..15, 1 -> ks 16..31
  const int bw = w & 3;                  // b-tile within K-group

  // stage A-fragments from n-major bf16 arrays; each wave reads full 64B lines
  for (int run = tid; run < 2048; run += 512) {
    int ll = run & 63, ks = run >> 6;
    int m = ll & 15;
    int n = (m & 3) * 1024 + bid * 4 + (m >> 2);
    int kb = ks * 32 + (ll >> 4) * 8;
    *(short8*)&U1l[run * 8] = *(const short8*)&U1t[(size_t)n * 1024 + kb];
    *(short8*)&W2l[run * 8] = *(const short8*)&W2t[(size_t)n * 1024 + kb];
    *(short8*)&U2l[run * 8] = *(const short8*)&U2t[(size_t)n * 1024 + kb];
  }
  for (int run = tid; run < 512; run += 512) {
    int ll = run & 63, ks = run >> 6;
    int m = ll & 15;
    int n = (m & 3) * 1024 + bid * 4 + (m >> 2);
    int kb = ks * 32 + (ll >> 4) * 8;
    *(short8*)&W1l[run * 8] = *(const short8*)&W1t[(size_t)n * 256 + kb];
  }
  __syncthreads();

  const int b = bw * 16 + (l & 15);
  const int jj = l >> 4;
  const int j = bid * 4 + jj;
  const int kq = jj * 8;
  const int ksBeg = kg * 16;             // this wave's half of the 32 ks-steps
  const int kBeg = kg * 4;               // this wave's half of the 8 W1 k-steps
  const int ridx = bw * 64 + l;          // reduce slot, shared by kg0/kg1 partners
  float c1 = c0_1[b * 1024 + j];
  float c2 = c0_2[b * 1024 + j];
  float b1r[4], b2r[4];
#pragma unroll
  for (int g = 0; g < 4; ++g) { b1r[g] = b1[g * 1024 + j]; b2r[g] = b2[g * 1024 + j]; }

  // ---- s = 0: layer-1 only ----
  {
    const unsigned short* er = ebf + ((size_t)b << 8);        // t=0 row
    const unsigned short* h1row = h1h + (size_t)b * 1024;     // slab 0
    short8 ev[4], h1v[16];
#pragma unroll
    for (int i = 0; i < 4; ++i) ev[i] = *(const short8*)&er[(kBeg + i) * 32 + kq];
#pragma unroll
    for (int i = 0; i < 16; ++i) h1v[i] = *(const short8*)&h1row[(ksBeg + i) * 32 + kq];
    floatx4 a1a = {0.f, 0.f, 0.f, 0.f}, a1b = a1a;
#pragma unroll
    for (int i = 0; i < 4; ++i) {
      short8 w1 = *(const short8*)&W1l[((kBeg + i) * 64 + l) * 8];
      if (i & 1) a1b = MFMA16(w1, ev[i], a1b); else a1a = MFMA16(w1, ev[i], a1a);
    }
#pragma unroll
    for (int i = 0; i < 16; ++i) {
      short8 u1 = *(const short8*)&U1l[((ksBeg + i) * 64 + l) * 8];
      if (i & 1) a1b = MFMA16(u1, h1v[i], a1b); else a1a = MFMA16(u1, h1v[i], a1a);
    }
    floatx4 z1p = a1a + a1b;
    if (kg) {
#pragma unroll
      for (int i = 0; i < 4; ++i) red[i * 256 + ridx] = z1p[i];
    }
    __syncthreads();
    if (!kg) {
      floatx4 z1 = z1p;
#pragma unroll
      for (int i = 0; i < 4; ++i) z1[i] += red[i * 256 + ridx];
      float ig = sigm(z1[0] + b1r[0]), fg = sigm(z1[1] + b1r[1]);
      float gg = tanh_f(z1[2] + b1r[2]), og = sigm(z1[3] + b1r[3]);
      c1 = fg * c1 + ig * gg;
      float h = og * tanh_f(c1);
      llc_store_u16(h1h + 65536 + (size_t)b * 1024 + j, f2bf(h));
    }
    gridbar(bar, 1u);
  }

  // ---- s = 1..127: both layers ----
  for (int s = 1; s < 128; ++s) {
    const unsigned short* er = ebf + ((size_t)(s * 64 + b) << 8);
    const unsigned short* h1row = h1h + (size_t)s * 65536 + (size_t)b * 1024;
    const unsigned short* h2row = h2h + (size_t)(s - 1) * 65536 + (size_t)b * 1024;
    short8 ev[4], h1v[16], h2v[16];
#pragma unroll
    for (int i = 0; i < 16; ++i) h1v[i] = *(const short8*)&h1row[(ksBeg + i) * 32 + kq];
#pragma unroll
    for (int i = 0; i < 16; ++i) h2v[i] = *(const short8*)&h2row[(ksBeg + i) * 32 + kq];
#pragma unroll
    for (int i = 0; i < 4; ++i) ev[i] = *(const short8*)&er[(kBeg + i) * 32 + kq];

    floatx4 a1a = {0.f, 0.f, 0.f, 0.f}, a1b = a1a;
    floatx4 a2a = a1a, a2b = a1a, a2c = a1a, a2d = a1a;
#pragma unroll
    for (int i = 0; i < 4; ++i) {
      short8 w1 = *(const short8*)&W1l[((kBeg + i) * 64 + l) * 8];
      if (i & 1) a1b = MFMA16(w1, ev[i], a1b); else a1a = MFMA16(w1, ev[i], a1a);
    }
#pragma unroll
    for (int i = 0; i < 16; ++i) {
      short8 u1 = *(const short8*)&U1l[((ksBeg + i) * 64 + l) * 8];
      short8 w2 = *(const short8*)&W2l[((ksBeg + i) * 64 + l) * 8];
      short8 u2 = *(const short8*)&U2l[((ksBeg + i) * 64 + l) * 8];
      if (i & 1) {
        a1b = MFMA16(u1, h1v[i], a1b);
        a2b = MFMA16(w2, h1v[i], a2b);
        a2d = MFMA16(u2, h2v[i], a2d);
      } else {
        a1a = MFMA16(u1, h1v[i], a1a);
        a2a = MFMA16(w2, h1v[i], a2a);
        a2c = MFMA16(u2, h2v[i], a2c);
      }
    }
    floatx4 z1p = a1a + a1b, z2p = (a2a + a2b) + (a2c + a2d);
    if (kg) {
#pragma unroll
      for (int i = 0; i < 4; ++i) red[i * 256 + ridx] = z1p[i];
#pragma unroll
      for (int i = 0; i < 4; ++i) red[(i + 4) * 256 + ridx] = z2p[i];
    }
    __syncthreads();
    if (!kg) {
      floatx4 z1 = z1p, z2 = z2p;
#pragma unroll
      for (int i = 0; i < 4; ++i) z1[i] += red[i * 256 + ridx];
#pragma unroll
      for (int i = 0; i < 4; ++i) z2[i] += red[(i + 4) * 256 + ridx];
      {
        float ig = sigm(z1[0] + b1r[0]), fg = sigm(z1[1] + b1r[1]);
        float gg = tanh_f(z1[2] + b1r[2]), og = sigm(z1[3] + b1r[3]);
        c1 = fg * c1 + ig * gg;
        float h = og * tanh_f(c1);
        llc_store_u16(h1h + (size_t)(s + 1) * 65536 + (size_t)b * 1024 + j, f2bf(h));
        if (s == 127) { hT1[b * 1024 + j] = h; cT1[b * 1024 + j] = c1; }
      }
      {
        float ig = sigm(z2[0] + b2r[0]), fg = sigm(z2[1] + b2r[1]);
        float gg = tanh_f(z2[2] + b2r[2]), og = sigm(z2[3] + b2r[3]);
        c2 = fg * c2 + ig * gg;
        float h = og * tanh_f(c2);
        llc_store_u16(h2h + (size_t)s * 65536 + (size_t)b * 1024 + j, f2bf(h));
        outy[(size_t)b * 131072 + (size_t)(s - 1) * 1024 + j] = h;
      }
    }
    gridbar(bar, (unsigned int)(s + 1));
  }

  // ---- s = 128: layer-2 only ----
  {
    const unsigned short* h1row = h1h + (size_t)128 * 65536 + (size_t)b * 1024;
    const unsigned short* h2row = h2h + (size_t)127 * 65536 + (size_t)b * 1024;
    short8 h1v[16], h2v[16];
#pragma unroll
    for (int i = 0; i < 16; ++i) h1v[i] = *(const short8*)&h1row[(ksBeg + i) * 32 + kq];
#pragma unroll
    for (int i = 0; i < 16; ++i) h2v[i] = *(const short8*)&h2row[(ksBeg + i) * 32 + kq];
    floatx4 a2a = {0.f, 0.f, 0.f, 0.f}, a2b = a2a, a2c = a2a, a2d = a2a;
#pragma unroll
    for (int i = 0; i < 16; ++i) {
      short8 w2 = *(const short8*)&W2l[((ksBeg + i) * 64 + l) * 8];
      short8 u2 = *(const short8*)&U2l[((ksBeg + i) * 64 + l) * 8];
      if (i & 1) { a2b = MFMA16(w2, h1v[i], a2b); a2d = MFMA16(u2, h2v[i], a2d); }
      else        { a2a = MFMA16(w2, h1v[i], a2a); a2c = MFMA16(u2, h2v[i], a2c); }
    }
    floatx4 z2p = (a2a + a2b) + (a2c + a2d);
    if (kg) {
#pragma unroll
      for (int i = 0; i < 4; ++i) red[i * 256 + ridx] = z2p[i];
    }
    __syncthreads();
    if (!kg) {
      floatx4 z2 = z2p;
#pragma unroll
      for (int i = 0; i < 4; ++i) z2[i] += red[i * 256 + ridx];
      float ig = sigm(z2[0] + b2r[0]), fg = sigm(z2[1] + b2r[1]);
      float gg = tanh_f(z2[2] + b2r[2]), og = sigm(z2[3] + b2r[3]);
      c2 = fg * c2 + ig * gg;
      float h = og * tanh_f(c2);
      outy[(size_t)b * 131072 + (size_t)127 * 1024 + j] = h;
      hT2[b * 1024 + j] = h;
      cT2[b * 1024 + j] = c2;
    }
  }
}

// ---------------- launch ----------------
extern "C" void kernel_launch(void* const* d_in, const int* in_sizes, int n_in,
                              void* d_out, int out_size, void* d_ws, size_t ws_size,
                              hipStream_t stream) {
  const int*   x    = (const int*)d_in[0];
  const float* h0_1 = (const float*)d_in[1];
  const float* c0_1 = (const float*)d_in[2];
  const float* h0_2 = (const float*)d_in[3];
  const float* c0_2 = (const float*)d_in[4];
  const float* emb  = (const float*)d_in[5];
  const float* W1   = (const float*)d_in[6];
  const float* U1   = (const float*)d_in[7];
  const float* b1   = (const float*)d_in[8];
  const float* W2   = (const float*)d_in[9];
  const float* U2   = (const float*)d_in[10];
  const float* b2   = (const float*)d_in[11];
  float* outf = (float*)d_out;

  unsigned short* ws  = (unsigned short*)d_ws;
  unsigned short* ebf = ws;                    //  2,097,152 ush
  unsigned short* W1t = ws +  2097152;         //  1,048,576
  unsigned short* U1t = ws +  3145728;         //  4,194,304
  unsigned short* W2t = ws +  7340032;         //  4,194,304
  unsigned short* U2t = ws + 11534336;         //  4,194,304
  unsigned short* h1h = ws + 15728640;         //  8,454,144
  unsigned short* h2h = ws + 24182784;         //  8,454,144
  unsigned int*   bar = (unsigned int*)(ws + 32636928);  // 4 KB (total ~65.3 MB)

  float* hT1 = outf + 8388608;
  float* cT1 = outf + 8454144;
  float* hT2 = outf + 8519680;
  float* cT2 = outf + 8585216;

  zero_bar<<<4, 256, 0, stream>>>(bar);
  prep_e<<<1024, 256, 0, stream>>>(x, emb, ebf);
  prep_wt<<<512,  256, 0, stream>>>(W1, W1t, 256);
  prep_wt<<<2048, 256, 0, stream>>>(U1, U1t, 1024);
  prep_wt<<<2048, 256, 0, stream>>>(W2, W2t, 1024);
  prep_wt<<<2048, 256, 0, stream>>>(U2, U2t, 1024);
  prep_cvt<<<256, 256, 0, stream>>>(h0_1, h1h);
  prep_cvt<<<256, 256, 0, stream>>>(h0_2, h2h);

  // allow 112 KB dynamic LDS (gfx950 has 160 KB/CU)
  static bool attr_done = false;
  if (!attr_done) {
    (void)hipFuncSetAttribute((const void*)lstm_fused,
                              hipFuncAttributeMaxDynamicSharedMemorySize, 114688);
    attr_done = true;
  }

  {
    const unsigned short *w1c = W1t, *u1c = U1t, *w2c = W2t, *u2c = U2t, *ec = ebf;
    unsigned short *h1c = h1h, *h2c = h2h;
    const float *c01 = c0_1, *c02 = c0_2, *b1c = b1, *b2c = b2;
    float *oy = outf, *ht1 = hT1, *ct1 = cT1, *ht2 = hT2, *ct2 = cT2;
    unsigned int* brc = bar;
    void* args[] = {&w1c, &u1c, &w2c, &u2c, &ec, &h1c, &h2c,
                    &c01, &c02, &b1c, &b2c, &oy, &ht1, &ct1, &ht2, &ct2, &brc};
    hipError_t e = hipLaunchCooperativeKernel((void*)lstm_fused, dim3(256), dim3(512),
                                              args, 114688, stream);
    if (e != hipSuccess) {
      // Defensive fallback: 256 blocks x 112 KB LDS = 1 block/CU on 256 CUs,
      // so all blocks are co-resident under a plain launch too; the gridbar
      // remains safe. Avoids silent no-op if the cooperative capacity check
      // rejects the 512-thread configuration.
      lstm_fused<<<dim3(256), dim3(512), 114688, stream>>>(
          w1c, u1c, w2c, u2c, ec, h1c, h2c, c01, c02, b1c, b2c,
          oy, ht1, ct1, ht2, ct2, brc);
    }
  }
}

// Round 6
// 1886.105 us; speedup vs baseline: 1.0839x; 1.0839x over previous
//
#include <hip/hip_runtime.h>

typedef __attribute__((ext_vector_type(8))) short short8;
typedef __attribute__((ext_vector_type(4))) float floatx4;

#define MFMA16(a, b, acc) __builtin_amdgcn_mfma_f32_16x16x32_bf16((a), (b), (acc), 0, 0, 0)

__device__ __forceinline__ float bf2f(unsigned short u) {
  union { float f; unsigned int i; } v; v.i = ((unsigned int)u) << 16; return v.f;
}
__device__ __forceinline__ unsigned short f2bf(float f) {
  union { float f; unsigned int i; } v; v.f = f;
  unsigned int r = (v.i + 0x7fffu + ((v.i >> 16) & 1u)) >> 16;
  return (unsigned short)r;
}
__device__ __forceinline__ float sigm(float x) { return 1.0f / (1.0f + __expf(-x)); }
__device__ __forceinline__ float tanh_f(float x) { return 2.0f * sigm(2.0f * x) - 1.0f; }

// write-through 2B store: no L2 allocation, lands at LLC (coherence point)
__device__ __forceinline__ void llc_store_u16(unsigned short* p, unsigned short v) {
  unsigned int v32 = v;
  asm volatile("global_store_short %0, %1, off sc0 sc1" :: "v"(p), "v"(v32) : "memory");
}

// ---------------- counter barrier: 1 hop, R0-level poll traffic ----------------
// Arrival: entry __syncthreads drains vmcnt(0) per wave (h stores ACK'd at the
// coherence point), then each block's t0 issues ONE fire-and-forget atomicAdd
// on bar[0] (result unused -> non-returning global_atomic_add; no return RTT).
// Notice: each block's t0 (single-lane wave -- same poll population and
// traffic as R0's proven `gen` poll) polls bar[0] until cnt >= 256*phase.
// vs R0 hierarchical: deletes the leader-hop and root-hop (~2 serialized
// store-visibility + poll-discovery links per step). vs R5 flat: poll traffic
// is 256 single-lane loads on ONE line, not 256 full waves on 16 lines.
// Phases monotonic; cnt grows to 128*256 = 32768 (no overflow). All blocks'
// h stores are LLC-visible before their add, so cnt==target implies all
// producer data for this phase is globally readable.
__device__ __forceinline__ void gridbar(unsigned int* bar, unsigned int phase) {
  __syncthreads();                     // compiler emits vmcnt(0) drain before s_barrier
  if (threadIdx.x == 0) {
    __hip_atomic_fetch_add(&bar[0], 1u, __ATOMIC_RELAXED, __HIP_MEMORY_SCOPE_AGENT);
    const unsigned int target = phase << 8;   // phase * 256 blocks
    while (__hip_atomic_load(&bar[0], __ATOMIC_RELAXED, __HIP_MEMORY_SCOPE_AGENT) < target)
      __builtin_amdgcn_s_sleep(1);
  }
  asm volatile("" ::: "memory");       // no load hoisting above the poll
  __syncthreads();
}

__global__ void zero_bar(unsigned int* bar) {
  int i = blockIdx.x * 256 + threadIdx.x;
  if (i < 1024) bar[i] = 0u;
}

// ---------------- prep kernels ----------------

// ebf[m=t*64+b][k] = bf16(emb[x[b][t]][k])
__global__ void prep_e(const int* __restrict__ x, const float* __restrict__ emb,
                       unsigned short* __restrict__ ebf) {
  int idx = blockIdx.x * 256 + threadIdx.x;   // [0, 8192*32)
  int koct = idx & 31;
  int m = idx >> 5;
  int t = m >> 6, b = m & 63;
  int tok = x[b * 128 + t];
  const float* src = emb + (size_t)tok * 256 + (size_t)koct * 8;
  short8 v;
#pragma unroll
  for (int j = 0; j < 8; ++j) v[j] = (short)f2bf(src[j]);
  *(short8*)(ebf + (size_t)m * 256 + koct * 8) = v;
}

// Wt[n][k] = bf16(W[k][n]); W is [K][4096]
__global__ void prep_wt(const float* __restrict__ W, unsigned short* __restrict__ Wt, int K) {
  int idx = blockIdx.x * 256 + threadIdx.x;   // [0, 4096*(K/8))
  int n = idx & 4095;
  int koct = idx >> 12;
  short8 v;
#pragma unroll
  for (int j = 0; j < 8; ++j) v[j] = (short)f2bf(W[(size_t)(koct * 8 + j) * 4096 + n]);
  *(short8*)(Wt + (size_t)n * K + koct * 8) = v;
}

__global__ void prep_cvt(const float* __restrict__ s, unsigned short* __restrict__ d) {
  int i = blockIdx.x * 256 + threadIdx.x;
  d[i] = f2bf(s[i]);
}

// ---------------- fused two-layer LSTM (one cooperative dispatch) ----------------
// Block bid owns j-quad = bid*4..bid*4+3 for BOTH layers. Super-step s:
//   layer-1: y1[s] from e[s] + h1 (slab s);  layer-2: out[s-1] from y1[s-1]
//   (= slab s, SAME loads) + h2 (slab s-1). 128 barriers total.
// Base structure = R0 (256 threads, best measured 1486 us). THIS REV (isolated
// change): gridbar = counter barrier (1 notification hop, low poll traffic).
__global__ __launch_bounds__(256, 1) void lstm_fused(
    const unsigned short* __restrict__ W1t,  // [4096][256]  bf16
    const unsigned short* __restrict__ U1t,  // [4096][1024] bf16
    const unsigned short* __restrict__ W2t,  // [4096][1024] bf16
    const unsigned short* __restrict__ U2t,  // [4096][1024] bf16
    const unsigned short* __restrict__ ebf,  // [8192][256]  bf16
    unsigned short* __restrict__ h1h,        // [129][64][1024], slab 0 prefilled
    unsigned short* __restrict__ h2h,        // [129][64][1024], slab 0 prefilled
    const float* __restrict__ c0_1, const float* __restrict__ c0_2,
    const float* __restrict__ b1,   const float* __restrict__ b2,
    float* __restrict__ outy,                 // [64][128][1024]
    float* __restrict__ hT1, float* __restrict__ cT1,
    float* __restrict__ hT2, float* __restrict__ cT2,
    unsigned int* __restrict__ bar) {
  extern __shared__ __align__(16) unsigned short lds[];   // 104 KB
  unsigned short* U1l = lds;             // 32 KB
  unsigned short* W2l = lds + 16384;     // 32 KB
  unsigned short* U2l = lds + 32768;     // 32 KB
  unsigned short* W1l = lds + 49152;     // 8 KB
  const int bid = blockIdx.x, tid = threadIdx.x;
  const int w = tid >> 6, l = tid & 63;

  // stage A-fragments from n-major bf16 arrays; each wave reads full 64B lines
  for (int run = tid; run < 2048; run += 256) {
    int ll = run & 63, ks = run >> 6;
    int m = ll & 15;
    int n = (m & 3) * 1024 + bid * 4 + (m >> 2);
    int kb = ks * 32 + (ll >> 4) * 8;
    *(short8*)&U1l[run * 8] = *(const short8*)&U1t[(size_t)n * 1024 + kb];
    *(short8*)&W2l[run * 8] = *(const short8*)&W2t[(size_t)n * 1024 + kb];
    *(short8*)&U2l[run * 8] = *(const short8*)&U2t[(size_t)n * 1024 + kb];
  }
  for (int run = tid; run < 512; run += 256) {
    int ll = run & 63, ks = run >> 6;
    int m = ll & 15;
    int n = (m & 3) * 1024 + bid * 4 + (m >> 2);
    int kb = ks * 32 + (ll >> 4) * 8;
    *(short8*)&W1l[run * 8] = *(const short8*)&W1t[(size_t)n * 256 + kb];
  }
  __syncthreads();

  const int b = w * 16 + (l & 15);
  const int jj = l >> 4;
  const int j = bid * 4 + jj;
  const int kq = jj * 8;
  float c1 = c0_1[b * 1024 + j];
  float c2 = c0_2[b * 1024 + j];
  float b1r[4], b2r[4];
#pragma unroll
  for (int g = 0; g < 4; ++g) { b1r[g] = b1[g * 1024 + j]; b2r[g] = b2[g * 1024 + j]; }

  // ---- s = 0: layer-1 only ----
  {
    const unsigned short* er = ebf + ((size_t)b << 8);        // t=0 row
    const unsigned short* h1row = h1h + (size_t)b * 1024;     // slab 0
    short8 ev[8], h1v[32];
#pragma unroll
    for (int k = 0; k < 8; ++k) ev[k] = *(const short8*)&er[k * 32 + kq];
#pragma unroll
    for (int ks = 0; ks < 32; ++ks) h1v[ks] = *(const short8*)&h1row[ks * 32 + kq];
    floatx4 a1a = {0.f, 0.f, 0.f, 0.f}, a1b = a1a;
#pragma unroll
    for (int k = 0; k < 8; ++k) {
      short8 w1 = *(const short8*)&W1l[(k * 64 + l) * 8];
      if (k & 1) a1b = MFMA16(w1, ev[k], a1b); else a1a = MFMA16(w1, ev[k], a1a);
    }
#pragma unroll
    for (int ks = 0; ks < 32; ++ks) {
      short8 u1 = *(const short8*)&U1l[(ks * 64 + l) * 8];
      if (ks & 1) a1b = MFMA16(u1, h1v[ks], a1b); else a1a = MFMA16(u1, h1v[ks], a1a);
    }
    floatx4 z1 = a1a + a1b;
    float ig = sigm(z1[0] + b1r[0]), fg = sigm(z1[1] + b1r[1]);
    float gg = tanh_f(z1[2] + b1r[2]), og = sigm(z1[3] + b1r[3]);
    c1 = fg * c1 + ig * gg;
    float h = og * tanh_f(c1);
    llc_store_u16(h1h + 65536 + (size_t)b * 1024 + j, f2bf(h));
    gridbar(bar, 1u);
  }

  // ---- s = 1..127: both layers ----
  for (int s = 1; s < 128; ++s) {
    const unsigned short* er = ebf + ((size_t)(s * 64 + b) << 8);
    const unsigned short* h1row = h1h + (size_t)s * 65536 + (size_t)b * 1024;
    const unsigned short* h2row = h2h + (size_t)(s - 1) * 65536 + (size_t)b * 1024;
    // bulk prefetch: issue ALL global loads for this step back-to-back
    short8 ev[8], h1v[32], h2v[32];
#pragma unroll
    for (int ks = 0; ks < 32; ++ks) h1v[ks] = *(const short8*)&h1row[ks * 32 + kq];
#pragma unroll
    for (int ks = 0; ks < 32; ++ks) h2v[ks] = *(const short8*)&h2row[ks * 32 + kq];
#pragma unroll
    for (int k = 0; k < 8; ++k) ev[k] = *(const short8*)&er[k * 32 + kq];

    floatx4 a1a = {0.f, 0.f, 0.f, 0.f}, a1b = a1a;
    floatx4 a2a = a1a, a2b = a1a, a2c = a1a, a2d = a1a;
#pragma unroll
    for (int k = 0; k < 8; ++k) {
      short8 w1 = *(const short8*)&W1l[(k * 64 + l) * 8];
      if (k & 1) a1b = MFMA16(w1, ev[k], a1b); else a1a = MFMA16(w1, ev[k], a1a);
    }
#pragma unroll
    for (int ks = 0; ks < 32; ++ks) {
      short8 u1 = *(const short8*)&U1l[(ks * 64 + l) * 8];
      short8 w2 = *(const short8*)&W2l[(ks * 64 + l) * 8];
      short8 u2 = *(const short8*)&U2l[(ks * 64 + l) * 8];
      if (ks & 1) {
        a1b = MFMA16(u1, h1v[ks], a1b);
        a2b = MFMA16(w2, h1v[ks], a2b);
        a2d = MFMA16(u2, h2v[ks], a2d);
      } else {
        a1a = MFMA16(u1, h1v[ks], a1a);
        a2a = MFMA16(w2, h1v[ks], a2a);
        a2c = MFMA16(u2, h2v[ks], a2c);
      }
    }
    floatx4 z1 = a1a + a1b, z2 = (a2a + a2b) + (a2c + a2d);
    {
      float ig = sigm(z1[0] + b1r[0]), fg = sigm(z1[1] + b1r[1]);
      float gg = tanh_f(z1[2] + b1r[2]), og = sigm(z1[3] + b1r[3]);
      c1 = fg * c1 + ig * gg;
      float h = og * tanh_f(c1);
      llc_store_u16(h1h + (size_t)(s + 1) * 65536 + (size_t)b * 1024 + j, f2bf(h));
      if (s == 127) { hT1[b * 1024 + j] = h; cT1[b * 1024 + j] = c1; }
    }
    {
      float ig = sigm(z2[0] + b2r[0]), fg = sigm(z2[1] + b2r[1]);
      float gg = tanh_f(z2[2] + b2r[2]), og = sigm(z2[3] + b2r[3]);
      c2 = fg * c2 + ig * gg;
      float h = og * tanh_f(c2);
      llc_store_u16(h2h + (size_t)s * 65536 + (size_t)b * 1024 + j, f2bf(h));
      outy[(size_t)b * 131072 + (size_t)(s - 1) * 1024 + j] = h;
    }
    gridbar(bar, (unsigned int)(s + 1));
  }

  // ---- s = 128: layer-2 only ----
  {
    const unsigned short* h1row = h1h + (size_t)128 * 65536 + (size_t)b * 1024;
    const unsigned short* h2row = h2h + (size_t)127 * 65536 + (size_t)b * 1024;
    short8 h1v[32], h2v[32];
#pragma unroll
    for (int ks = 0; ks < 32; ++ks) h1v[ks] = *(const short8*)&h1row[ks * 32 + kq];
#pragma unroll
    for (int ks = 0; ks < 32; ++ks) h2v[ks] = *(const short8*)&h2row[ks * 32 + kq];
    floatx4 a2a = {0.f, 0.f, 0.f, 0.f}, a2b = a2a, a2c = a2a, a2d = a2a;
#pragma unroll
    for (int ks = 0; ks < 32; ++ks) {
      short8 w2 = *(const short8*)&W2l[(ks * 64 + l) * 8];
      short8 u2 = *(const short8*)&U2l[(ks * 64 + l) * 8];
      if (ks & 1) { a2b = MFMA16(w2, h1v[ks], a2b); a2d = MFMA16(u2, h2v[ks], a2d); }
      else        { a2a = MFMA16(w2, h1v[ks], a2a); a2c = MFMA16(u2, h2v[ks], a2c); }
    }
    floatx4 z2 = (a2a + a2b) + (a2c + a2d);
    float ig = sigm(z2[0] + b2r[0]), fg = sigm(z2[1] + b2r[1]);
    float gg = tanh_f(z2[2] + b2r[2]), og = sigm(z2[3] + b2r[3]);
    c2 = fg * c2 + ig * gg;
    float h = og * tanh_f(c2);
    outy[(size_t)b * 131072 + (size_t)127 * 1024 + j] = h;
    hT2[b * 1024 + j] = h;
    cT2[b * 1024 + j] = c2;
  }
}

// ---------------- launch ----------------
extern "C" void kernel_launch(void* const* d_in, const int* in_sizes, int n_in,
                              void* d_out, int out_size, void* d_ws, size_t ws_size,
                              hipStream_t stream) {
  const int*   x    = (const int*)d_in[0];
  const float* h0_1 = (const float*)d_in[1];
  const float* c0_1 = (const float*)d_in[2];
  const float* h0_2 = (const float*)d_in[3];
  const float* c0_2 = (const float*)d_in[4];
  const float* emb  = (const float*)d_in[5];
  const float* W1   = (const float*)d_in[6];
  const float* U1   = (const float*)d_in[7];
  const float* b1   = (const float*)d_in[8];
  const float* W2   = (const float*)d_in[9];
  const float* U2   = (const float*)d_in[10];
  const float* b2   = (const float*)d_in[11];
  float* outf = (float*)d_out;

  unsigned short* ws  = (unsigned short*)d_ws;
  unsigned short* ebf = ws;                    //  2,097,152 ush
  unsigned short* W1t = ws +  2097152;         //  1,048,576
  unsigned short* U1t = ws +  3145728;         //  4,194,304
  unsigned short* W2t = ws +  7340032;         //  4,194,304
  unsigned short* U2t = ws + 11534336;         //  4,194,304
  unsigned short* h1h = ws + 15728640;         //  8,454,144
  unsigned short* h2h = ws + 24182784;         //  8,454,144
  unsigned int*   bar = (unsigned int*)(ws + 32636928);  // 4 KB (total ~65.3 MB)

  float* hT1 = outf + 8388608;
  float* cT1 = outf + 8454144;
  float* hT2 = outf + 8519680;
  float* cT2 = outf + 8585216;

  zero_bar<<<4, 256, 0, stream>>>(bar);
  prep_e<<<1024, 256, 0, stream>>>(x, emb, ebf);
  prep_wt<<<512,  256, 0, stream>>>(W1, W1t, 256);
  prep_wt<<<2048, 256, 0, stream>>>(U1, U1t, 1024);
  prep_wt<<<2048, 256, 0, stream>>>(W2, W2t, 1024);
  prep_wt<<<2048, 256, 0, stream>>>(U2, U2t, 1024);
  prep_cvt<<<256, 256, 0, stream>>>(h0_1, h1h);
  prep_cvt<<<256, 256, 0, stream>>>(h0_2, h2h);

  // allow 104 KB dynamic LDS (gfx950 has 160 KB/CU)
  static bool attr_done = false;
  if (!attr_done) {
    (void)hipFuncSetAttribute((const void*)lstm_fused,
                              hipFuncAttributeMaxDynamicSharedMemorySize, 106496);
    attr_done = true;
  }

  {
    const unsigned short *w1c = W1t, *u1c = U1t, *w2c = W2t, *u2c = U2t, *ec = ebf;
    unsigned short *h1c = h1h, *h2c = h2h;
    const float *c01 = c0_1, *c02 = c0_2, *b1c = b1, *b2c = b2;
    float *oy = outf, *ht1 = hT1, *ct1 = cT1, *ht2 = hT2, *ct2 = cT2;
    unsigned int* brc = bar;
    void* args[] = {&w1c, &u1c, &w2c, &u2c, &ec, &h1c, &h2c,
                    &c01, &c02, &b1c, &b2c, &oy, &ht1, &ct1, &ht2, &ct2, &brc};
    hipError_t e = hipLaunchCooperativeKernel((void*)lstm_fused, dim3(256), dim3(256),
                                              args, 106496, stream);
    if (e != hipSuccess) {
      // Defensive fallback: 256 blocks x 104 KB LDS = 1 block/CU on 256 CUs,
      // so all blocks are co-resident under a plain launch too; the gridbar
      // remains safe.
      lstm_fused<<<dim3(256), dim3(256), 106496, stream>>>(
          w1c, u1c, w2c, u2c, ec, h1c, h2c, c01, c02, b1c, b2c,
          oy, ht1, ct1, ht2, ct2, brc);
    }
  }
}

// Round 7
// 1655.005 us; speedup vs baseline: 1.2352x; 1.1396x over previous
//
#include <hip/hip_runtime.h>

typedef __attribute__((ext_vector_type(8))) short short8;
typedef __attribute__((ext_vector_type(4))) float floatx4;

#define MFMA16(a, b, acc) __builtin_amdgcn_mfma_f32_16x16x32_bf16((a), (b), (acc), 0, 0, 0)

__device__ __forceinline__ float bf2f(unsigned short u) {
  union { float f; unsigned int i; } v; v.i = ((unsigned int)u) << 16; return v.f;
}
__device__ __forceinline__ unsigned short f2bf(float f) {
  union { float f; unsigned int i; } v; v.f = f;
  unsigned int r = (v.i + 0x7fffu + ((v.i >> 16) & 1u)) >> 16;
  return (unsigned short)r;
}
__device__ __forceinline__ float sigm(float x) { return 1.0f / (1.0f + __expf(-x)); }
__device__ __forceinline__ float tanh_f(float x) { return 2.0f * sigm(2.0f * x) - 1.0f; }

// write-through 2B store: no L2 allocation, lands at LLC (coherence point)
__device__ __forceinline__ void llc_store_u16(unsigned short* p, unsigned short v) {
  unsigned int v32 = v;
  asm volatile("global_store_short %0, %1, off sc0 sc1" :: "v"(p), "v"(v32) : "memory");
}

// ---------------- hierarchical checker barrier (R0-proven, verbatim) ----------------
// flags[0..255] (lines 0-15) <- every block's t0.
// 8 leaders (bid%32==0): wave0 polls its group's 32 flags -> gflags[g] (line 16+).
// root (bid 0): polls gflags[0..7] -> gen (line 32).
// everyone: t0 polls gen. R5/R6 established: flat-poll and counter variants are
// each 2-3.5 us/step WORSE (poll flooding / arrival serialization). Keep this.
__device__ __forceinline__ void gridbar(unsigned int* bar, unsigned int phase) {
  __syncthreads();                     // compiler emits vmcnt(0) drain before s_barrier
  const unsigned int bid = blockIdx.x;
  const unsigned int tid = threadIdx.x;
  unsigned int* flags  = bar;          // 256 dwords
  unsigned int* gflags = bar + 256;    // 8 dwords (line 16)
  unsigned int* gen    = bar + 512;    // line 32
  if (tid == 0)
    __hip_atomic_store(&flags[bid], phase, __ATOMIC_RELAXED, __HIP_MEMORY_SCOPE_AGENT);
  asm volatile("" ::: "memory");
  if ((bid & 31u) == 0u && tid < 64) {         // leader wave
    const unsigned int g = bid >> 5;
    unsigned int v;
    do {
      v = __hip_atomic_load(&flags[g * 32 + (tid & 31)], __ATOMIC_RELAXED, __HIP_MEMORY_SCOPE_AGENT);
      if (v < phase) __builtin_amdgcn_s_sleep(1);
    } while (__all(v >= phase) == 0);
    if (tid == 0)
      __hip_atomic_store(&gflags[g], phase, __ATOMIC_RELAXED, __HIP_MEMORY_SCOPE_AGENT);
    if (bid == 0) {                            // root
      unsigned int gv;
      do {
        gv = __hip_atomic_load(&gflags[tid & 7], __ATOMIC_RELAXED, __HIP_MEMORY_SCOPE_AGENT);
        if (gv < phase) __builtin_amdgcn_s_sleep(1);
      } while (__all(gv >= phase) == 0);
      if (tid == 0)
        __hip_atomic_store(gen, phase, __ATOMIC_RELAXED, __HIP_MEMORY_SCOPE_AGENT);
    }
  }
  if (tid == 0) {
    while (__hip_atomic_load(gen, __ATOMIC_RELAXED, __HIP_MEMORY_SCOPE_AGENT) < phase)
      __builtin_amdgcn_s_sleep(1);
  }
  asm volatile("" ::: "memory");       // no load hoisting above the poll
  __syncthreads();
}

__global__ void zero_bar(unsigned int* bar) {
  int i = blockIdx.x * 256 + threadIdx.x;
  if (i < 1024) bar[i] = 0u;
}

// ---------------- prep kernels ----------------

// ebf[m=t*64+b][k] = bf16(emb[x[b][t]][k])
__global__ void prep_e(const int* __restrict__ x, const float* __restrict__ emb,
                       unsigned short* __restrict__ ebf) {
  int idx = blockIdx.x * 256 + threadIdx.x;   // [0, 8192*32)
  int koct = idx & 31;
  int m = idx >> 5;
  int t = m >> 6, b = m & 63;
  int tok = x[b * 128 + t];
  const float* src = emb + (size_t)tok * 256 + (size_t)koct * 8;
  short8 v;
#pragma unroll
  for (int j = 0; j < 8; ++j) v[j] = (short)f2bf(src[j]);
  *(short8*)(ebf + (size_t)m * 256 + koct * 8) = v;
}

// Wt[n][k] = bf16(W[k][n]); W is [K][4096]
__global__ void prep_wt(const float* __restrict__ W, unsigned short* __restrict__ Wt, int K) {
  int idx = blockIdx.x * 256 + threadIdx.x;   // [0, 4096*(K/8))
  int n = idx & 4095;
  int koct = idx >> 12;
  short8 v;
#pragma unroll
  for (int j = 0; j < 8; ++j) v[j] = (short)f2bf(W[(size_t)(koct * 8 + j) * 4096 + n]);
  *(short8*)(Wt + (size_t)n * K + koct * 8) = v;
}

__global__ void prep_cvt(const float* __restrict__ s, unsigned short* __restrict__ d) {
  int i = blockIdx.x * 256 + threadIdx.x;
  d[i] = f2bf(s[i]);
}

// ---------------- fused two-layer LSTM (one cooperative dispatch) ----------------
// Block bid owns j-quad = bid*4..bid*4+3 for BOTH layers. Super-step s:
//   layer-1: y1[s] from e[s] + h1 (slab s);  layer-2: out[s-1] from y1[s-1]
//   (= slab s, SAME loads) + h2 (slab s-1). 128 barriers total.
// Base = R0 (256 threads, hierarchical barrier; best measured 1486 us).
// THIS REV (isolated change): per-block ROTATED k-order for the h1/h2/e read
// burst AND its MFMA consumption. All 256 blocks read the SAME 256 KB of h
// slabs each step; with identical k-order all ~32 blocks of an XCD cold-miss
// the same lines simultaneously -> duplicated LLC fetches (~64 MB/step, the
// hypothesized BW bound; fits R4's null-TLP + R5/R6 barrier results). Rotation
// rot = (bid + (bid>>3)) & 31 spreads first-touch lines so each line is
// LLC-fetched ~once per XCD and L2-broadcast to the rest. Accumulation
// reorder is ulp-level. Register arrays stay statically indexed (rule #20);
// only LDS/global addresses carry the runtime rotation.
__global__ __launch_bounds__(256, 1) void lstm_fused(
    const unsigned short* __restrict__ W1t,  // [4096][256]  bf16
    const unsigned short* __restrict__ U1t,  // [4096][1024] bf16
    const unsigned short* __restrict__ W2t,  // [4096][1024] bf16
    const unsigned short* __restrict__ U2t,  // [4096][1024] bf16
    const unsigned short* __restrict__ ebf,  // [8192][256]  bf16
    unsigned short* __restrict__ h1h,        // [129][64][1024], slab 0 prefilled
    unsigned short* __restrict__ h2h,        // [129][64][1024], slab 0 prefilled
    const float* __restrict__ c0_1, const float* __restrict__ c0_2,
    const float* __restrict__ b1,   const float* __restrict__ b2,
    float* __restrict__ outy,                 // [64][128][1024]
    float* __restrict__ hT1, float* __restrict__ cT1,
    float* __restrict__ hT2, float* __restrict__ cT2,
    unsigned int* __restrict__ bar) {
  extern __shared__ __align__(16) unsigned short lds[];   // 104 KB
  unsigned short* U1l = lds;             // 32 KB
  unsigned short* W2l = lds + 16384;     // 32 KB
  unsigned short* U2l = lds + 32768;     // 32 KB
  unsigned short* W1l = lds + 49152;     // 8 KB
  const int bid = blockIdx.x, tid = threadIdx.x;
  const int w = tid >> 6, l = tid & 63;

  // stage A-fragments from n-major bf16 arrays; each wave reads full 64B lines
  for (int run = tid; run < 2048; run += 256) {
    int ll = run & 63, ks = run >> 6;
    int m = ll & 15;
    int n = (m & 3) * 1024 + bid * 4 + (m >> 2);
    int kb = ks * 32 + (ll >> 4) * 8;
    *(short8*)&U1l[run * 8] = *(const short8*)&U1t[(size_t)n * 1024 + kb];
    *(short8*)&W2l[run * 8] = *(const short8*)&W2t[(size_t)n * 1024 + kb];
    *(short8*)&U2l[run * 8] = *(const short8*)&U2t[(size_t)n * 1024 + kb];
  }
  for (int run = tid; run < 512; run += 256) {
    int ll = run & 63, ks = run >> 6;
    int m = ll & 15;
    int n = (m & 3) * 1024 + bid * 4 + (m >> 2);
    int kb = ks * 32 + (ll >> 4) * 8;
    *(short8*)&W1l[run * 8] = *(const short8*)&W1t[(size_t)n * 256 + kb];
  }
  __syncthreads();

  const int b = w * 16 + (l & 15);
  const int jj = l >> 4;
  const int j = bid * 4 + jj;
  const int kq = jj * 8;
  const int rot = (bid + (bid >> 3)) & 31;   // distinct per co-XCD block under
                                             // round-robin OR chunked dispatch
  float c1 = c0_1[b * 1024 + j];
  float c2 = c0_2[b * 1024 + j];
  float b1r[4], b2r[4];
#pragma unroll
  for (int g = 0; g < 4; ++g) { b1r[g] = b1[g * 1024 + j]; b2r[g] = b2[g * 1024 + j]; }

  // ---- s = 0: layer-1 only (unrotated, 1 of 129 steps) ----
  {
    const unsigned short* er = ebf + ((size_t)b << 8);        // t=0 row
    const unsigned short* h1row = h1h + (size_t)b * 1024;     // slab 0
    short8 ev[8], h1v[32];
#pragma unroll
    for (int k = 0; k < 8; ++k) ev[k] = *(const short8*)&er[k * 32 + kq];
#pragma unroll
    for (int ks = 0; ks < 32; ++ks) h1v[ks] = *(const short8*)&h1row[ks * 32 + kq];
    floatx4 a1a = {0.f, 0.f, 0.f, 0.f}, a1b = a1a;
#pragma unroll
    for (int k = 0; k < 8; ++k) {
      short8 w1 = *(const short8*)&W1l[(k * 64 + l) * 8];
      if (k & 1) a1b = MFMA16(w1, ev[k], a1b); else a1a = MFMA16(w1, ev[k], a1a);
    }
#pragma unroll
    for (int ks = 0; ks < 32; ++ks) {
      short8 u1 = *(const short8*)&U1l[(ks * 64 + l) * 8];
      if (ks & 1) a1b = MFMA16(u1, h1v[ks], a1b); else a1a = MFMA16(u1, h1v[ks], a1a);
    }
    floatx4 z1 = a1a + a1b;
    float ig = sigm(z1[0] + b1r[0]), fg = sigm(z1[1] + b1r[1]);
    float gg = tanh_f(z1[2] + b1r[2]), og = sigm(z1[3] + b1r[3]);
    c1 = fg * c1 + ig * gg;
    float h = og * tanh_f(c1);
    llc_store_u16(h1h + 65536 + (size_t)b * 1024 + j, f2bf(h));
    gridbar(bar, 1u);
  }

  // ---- s = 1..127: both layers, rotated k-order ----
  for (int s = 1; s < 128; ++s) {
    const unsigned short* er = ebf + ((size_t)(s * 64 + b) << 8);
    const unsigned short* h1row = h1h + (size_t)s * 65536 + (size_t)b * 1024;
    const unsigned short* h2row = h2h + (size_t)(s - 1) * 65536 + (size_t)b * 1024;
    // bulk prefetch in ROTATED order: h1v[i] holds data for ks=(rot+i)&31
    short8 ev[8], h1v[32], h2v[32];
#pragma unroll
    for (int i = 0; i < 32; ++i) {
      int ks = (rot + i) & 31;
      h1v[i] = *(const short8*)&h1row[ks * 32 + kq];
    }
#pragma unroll
    for (int i = 0; i < 32; ++i) {
      int ks = (rot + i) & 31;
      h2v[i] = *(const short8*)&h2row[ks * 32 + kq];
    }
#pragma unroll
    for (int i = 0; i < 8; ++i) {
      int k = ((rot & 7) + i) & 7;
      ev[i] = *(const short8*)&er[k * 32 + kq];
    }

    floatx4 a1a = {0.f, 0.f, 0.f, 0.f}, a1b = a1a;
    floatx4 a2a = a1a, a2b = a1a, a2c = a1a, a2d = a1a;
#pragma unroll
    for (int i = 0; i < 8; ++i) {
      int k = ((rot & 7) + i) & 7;
      short8 w1 = *(const short8*)&W1l[(k * 64 + l) * 8];
      if (i & 1) a1b = MFMA16(w1, ev[i], a1b); else a1a = MFMA16(w1, ev[i], a1a);
    }
#pragma unroll
    for (int i = 0; i < 32; ++i) {
      int ks = (rot + i) & 31;
      short8 u1 = *(const short8*)&U1l[(ks * 64 + l) * 8];
      short8 w2 = *(const short8*)&W2l[(ks * 64 + l) * 8];
      short8 u2 = *(const short8*)&U2l[(ks * 64 + l) * 8];
      if (i & 1) {
        a1b = MFMA16(u1, h1v[i], a1b);
        a2b = MFMA16(w2, h1v[i], a2b);
        a2d = MFMA16(u2, h2v[i], a2d);
      } else {
        a1a = MFMA16(u1, h1v[i], a1a);
        a2a = MFMA16(w2, h1v[i], a2a);
        a2c = MFMA16(u2, h2v[i], a2c);
      }
    }
    floatx4 z1 = a1a + a1b, z2 = (a2a + a2b) + (a2c + a2d);
    {
      float ig = sigm(z1[0] + b1r[0]), fg = sigm(z1[1] + b1r[1]);
      float gg = tanh_f(z1[2] + b1r[2]), og = sigm(z1[3] + b1r[3]);
      c1 = fg * c1 + ig * gg;
      float h = og * tanh_f(c1);
      llc_store_u16(h1h + (size_t)(s + 1) * 65536 + (size_t)b * 1024 + j, f2bf(h));
      if (s == 127) { hT1[b * 1024 + j] = h; cT1[b * 1024 + j] = c1; }
    }
    {
      float ig = sigm(z2[0] + b2r[0]), fg = sigm(z2[1] + b2r[1]);
      float gg = tanh_f(z2[2] + b2r[2]), og = sigm(z2[3] + b2r[3]);
      c2 = fg * c2 + ig * gg;
      float h = og * tanh_f(c2);
      llc_store_u16(h2h + (size_t)s * 65536 + (size_t)b * 1024 + j, f2bf(h));
      outy[(size_t)b * 131072 + (size_t)(s - 1) * 1024 + j] = h;
    }
    gridbar(bar, (unsigned int)(s + 1));
  }

  // ---- s = 128: layer-2 only (unrotated) ----
  {
    const unsigned short* h1row = h1h + (size_t)128 * 65536 + (size_t)b * 1024;
    const unsigned short* h2row = h2h + (size_t)127 * 65536 + (size_t)b * 1024;
    short8 h1v[32], h2v[32];
#pragma unroll
    for (int ks = 0; ks < 32; ++ks) h1v[ks] = *(const short8*)&h1row[ks * 32 + kq];
#pragma unroll
    for (int ks = 0; ks < 32; ++ks) h2v[ks] = *(const short8*)&h2row[ks * 32 + kq];
    floatx4 a2a = {0.f, 0.f, 0.f, 0.f}, a2b = a2a, a2c = a2a, a2d = a2a;
#pragma unroll
    for (int ks = 0; ks < 32; ++ks) {
      short8 w2 = *(const short8*)&W2l[(ks * 64 + l) * 8];
      short8 u2 = *(const short8*)&U2l[(ks * 64 + l) * 8];
      if (ks & 1) { a2b = MFMA16(w2, h1v[ks], a2b); a2d = MFMA16(u2, h2v[ks], a2d); }
      else        { a2a = MFMA16(w2, h1v[ks], a2a); a2c = MFMA16(u2, h2v[ks], a2c); }
    }
    floatx4 z2 = (a2a + a2b) + (a2c + a2d);
    float ig = sigm(z2[0] + b2r[0]), fg = sigm(z2[1] + b2r[1]);
    float gg = tanh_f(z2[2] + b2r[2]), og = sigm(z2[3] + b2r[3]);
    c2 = fg * c2 + ig * gg;
    float h = og * tanh_f(c2);
    outy[(size_t)b * 131072 + (size_t)127 * 1024 + j] = h;
    hT2[b * 1024 + j] = h;
    cT2[b * 1024 + j] = c2;
  }
}

// ---------------- launch ----------------
extern "C" void kernel_launch(void* const* d_in, const int* in_sizes, int n_in,
                              void* d_out, int out_size, void* d_ws, size_t ws_size,
                              hipStream_t stream) {
  const int*   x    = (const int*)d_in[0];
  const float* h0_1 = (const float*)d_in[1];
  const float* c0_1 = (const float*)d_in[2];
  const float* h0_2 = (const float*)d_in[3];
  const float* c0_2 = (const float*)d_in[4];
  const float* emb  = (const float*)d_in[5];
  const float* W1   = (const float*)d_in[6];
  const float* U1   = (const float*)d_in[7];
  const float* b1   = (const float*)d_in[8];
  const float* W2   = (const float*)d_in[9];
  const float* U2   = (const float*)d_in[10];
  const float* b2   = (const float*)d_in[11];
  float* outf = (float*)d_out;

  unsigned short* ws  = (unsigned short*)d_ws;
  unsigned short* ebf = ws;                    //  2,097,152 ush
  unsigned short* W1t = ws +  2097152;         //  1,048,576
  unsigned short* U1t = ws +  3145728;         //  4,194,304
  unsigned short* W2t = ws +  7340032;         //  4,194,304
  unsigned short* U2t = ws + 11534336;         //  4,194,304
  unsigned short* h1h = ws + 15728640;         //  8,454,144
  unsigned short* h2h = ws + 24182784;         //  8,454,144
  unsigned int*   bar = (unsigned int*)(ws + 32636928);  // 4 KB (total ~65.3 MB)

  float* hT1 = outf + 8388608;
  float* cT1 = outf + 8454144;
  float* hT2 = outf + 8519680;
  float* cT2 = outf + 8585216;

  zero_bar<<<4, 256, 0, stream>>>(bar);
  prep_e<<<1024, 256, 0, stream>>>(x, emb, ebf);
  prep_wt<<<512,  256, 0, stream>>>(W1, W1t, 256);
  prep_wt<<<2048, 256, 0, stream>>>(U1, U1t, 1024);
  prep_wt<<<2048, 256, 0, stream>>>(W2, W2t, 1024);
  prep_wt<<<2048, 256, 0, stream>>>(U2, U2t, 1024);
  prep_cvt<<<256, 256, 0, stream>>>(h0_1, h1h);
  prep_cvt<<<256, 256, 0, stream>>>(h0_2, h2h);

  // allow 104 KB dynamic LDS (gfx950 has 160 KB/CU)
  static bool attr_done = false;
  if (!attr_done) {
    (void)hipFuncSetAttribute((const void*)lstm_fused,
                              hipFuncAttributeMaxDynamicSharedMemorySize, 106496);
    attr_done = true;
  }

  {
    const unsigned short *w1c = W1t, *u1c = U1t, *w2c = W2t, *u2c = U2t, *ec = ebf;
    unsigned short *h1c = h1h, *h2c = h2h;
    const float *c01 = c0_1, *c02 = c0_2, *b1c = b1, *b2c = b2;
    float *oy = outf, *ht1 = hT1, *ct1 = cT1, *ht2 = hT2, *ct2 = cT2;
    unsigned int* brc = bar;
    void* args[] = {&w1c, &u1c, &w2c, &u2c, &ec, &h1c, &h2c,
                    &c01, &c02, &b1c, &b2c, &oy, &ht1, &ct1, &ht2, &ct2, &brc};
    hipError_t e = hipLaunchCooperativeKernel((void*)lstm_fused, dim3(256), dim3(256),
                                              args, 106496, stream);
    if (e != hipSuccess) {
      // Defensive fallback: 256 blocks x 104 KB LDS = 1 block/CU on 256 CUs,
      // so all blocks are co-resident under a plain launch too; the gridbar
      // remains safe.
      lstm_fused<<<dim3(256), dim3(256), 106496, stream>>>(
          w1c, u1c, w2c, u2c, ec, h1c, h2c, c01, c02, b1c, b2c,
          oy, ht1, ct1, ht2, ct2, brc);
    }
  }
}

// Round 8
// 1550.925 us; speedup vs baseline: 1.3181x; 1.0671x over previous
//
#include <hip/hip_runtime.h>

typedef __attribute__((ext_vector_type(8))) short short8;
typedef __attribute__((ext_vector_type(4))) float floatx4;

#define MFMA16(a, b, acc) __builtin_amdgcn_mfma_f32_16x16x32_bf16((a), (b), (acc), 0, 0, 0)

__device__ __forceinline__ float bf2f(unsigned short u) {
  union { float f; unsigned int i; } v; v.i = ((unsigned int)u) << 16; return v.f;
}
__device__ __forceinline__ unsigned short f2bf(float f) {
  union { float f; unsigned int i; } v; v.f = f;
  unsigned int r = (v.i + 0x7fffu + ((v.i >> 16) & 1u)) >> 16;
  return (unsigned short)r;
}
__device__ __forceinline__ float sigm(float x) { return 1.0f / (1.0f + __expf(-x)); }
__device__ __forceinline__ float tanh_f(float x) { return 2.0f * sigm(2.0f * x) - 1.0f; }

// write-through 8B store: no L2 allocation, lands at LLC (coherence point)
__device__ __forceinline__ void llc_store_u64(unsigned short* p, unsigned long long v) {
  asm volatile("global_store_dwordx2 %0, %1, off sc0 sc1" :: "v"(p), "v"(v) : "memory");
}

// ---------------- hierarchical checker barrier (R0-proven, verbatim) ----------------
// R5/R6 established: flat-poll and counter variants are 2-3.5 us/step WORSE
// (poll flooding / arrival serialization). Keep this one.
__device__ __forceinline__ void gridbar(unsigned int* bar, unsigned int phase) {
  __syncthreads();                     // compiler emits vmcnt(0) drain before s_barrier
  const unsigned int bid = blockIdx.x;
  const unsigned int tid = threadIdx.x;
  unsigned int* flags  = bar;          // 256 dwords
  unsigned int* gflags = bar + 256;    // 8 dwords (line 16)
  unsigned int* gen    = bar + 512;    // line 32
  if (tid == 0)
    __hip_atomic_store(&flags[bid], phase, __ATOMIC_RELAXED, __HIP_MEMORY_SCOPE_AGENT);
  asm volatile("" ::: "memory");
  if ((bid & 31u) == 0u && tid < 64) {         // leader wave
    const unsigned int g = bid >> 5;
    unsigned int v;
    do {
      v = __hip_atomic_load(&flags[g * 32 + (tid & 31)], __ATOMIC_RELAXED, __HIP_MEMORY_SCOPE_AGENT);
      if (v < phase) __builtin_amdgcn_s_sleep(1);
    } while (__all(v >= phase) == 0);
    if (tid == 0)
      __hip_atomic_store(&gflags[g], phase, __ATOMIC_RELAXED, __HIP_MEMORY_SCOPE_AGENT);
    if (bid == 0) {                            // root
      unsigned int gv;
      do {
        gv = __hip_atomic_load(&gflags[tid & 7], __ATOMIC_RELAXED, __HIP_MEMORY_SCOPE_AGENT);
        if (gv < phase) __builtin_amdgcn_s_sleep(1);
      } while (__all(gv >= phase) == 0);
      if (tid == 0)
        __hip_atomic_store(gen, phase, __ATOMIC_RELAXED, __HIP_MEMORY_SCOPE_AGENT);
    }
  }
  if (tid == 0) {
    while (__hip_atomic_load(gen, __ATOMIC_RELAXED, __HIP_MEMORY_SCOPE_AGENT) < phase)
      __builtin_amdgcn_s_sleep(1);
  }
  asm volatile("" ::: "memory");       // no load hoisting above the poll
  __syncthreads();
}

__global__ void zero_bar(unsigned int* bar) {
  int i = blockIdx.x * 256 + threadIdx.x;
  if (i < 1024) bar[i] = 0u;
}

// ---------------- prep kernels ----------------

// ebf[m=t*64+b][k] = bf16(emb[x[b][t]][k])
__global__ void prep_e(const int* __restrict__ x, const float* __restrict__ emb,
                       unsigned short* __restrict__ ebf) {
  int idx = blockIdx.x * 256 + threadIdx.x;   // [0, 8192*32)
  int koct = idx & 31;
  int m = idx >> 5;
  int t = m >> 6, b = m & 63;
  int tok = x[b * 128 + t];
  const float* src = emb + (size_t)tok * 256 + (size_t)koct * 8;
  short8 v;
#pragma unroll
  for (int j = 0; j < 8; ++j) v[j] = (short)f2bf(src[j]);
  *(short8*)(ebf + (size_t)m * 256 + koct * 8) = v;
}

// Wt[n][k] = bf16(W[k][n]); W is [K][4096]
__global__ void prep_wt(const float* __restrict__ W, unsigned short* __restrict__ Wt, int K) {
  int idx = blockIdx.x * 256 + threadIdx.x;   // [0, 4096*(K/8))
  int n = idx & 4095;
  int koct = idx >> 12;
  short8 v;
#pragma unroll
  for (int j = 0; j < 8; ++j) v[j] = (short)f2bf(W[(size_t)(koct * 8 + j) * 4096 + n]);
  *(short8*)(Wt + (size_t)n * K + koct * 8) = v;
}

__global__ void prep_cvt(const float* __restrict__ s, unsigned short* __restrict__ d) {
  int i = blockIdx.x * 256 + threadIdx.x;
  d[i] = f2bf(s[i]);
}

// out transpose: outy[b][s][j] = oscr[s][j][b]   (both f32, fully coalesced)
__global__ __launch_bounds__(256) void out_tr(const float* __restrict__ oscr,
                                              float* __restrict__ outy) {
  __shared__ float t[64][65];
  const int s = blockIdx.x & 127, jc = blockIdx.x >> 7;   // grid 2048 = 128 s x 16 jc
  const int tid = threadIdx.x;
  const int r0 = tid >> 6, cc = tid & 63;
#pragma unroll
  for (int r = 0; r < 16; ++r) {
    int jr = r * 4 + r0;
    t[jr][cc] = oscr[(size_t)s * 65536 + (size_t)(jc * 64 + jr) * 64 + cc];
  }
  __syncthreads();
#pragma unroll
  for (int r = 0; r < 16; ++r) {
    int br = r * 4 + r0;
    outy[(size_t)br * 131072 + (size_t)s * 1024 + jc * 64 + cc] = t[cc][br];
  }
}

// ---------------- fused two-layer LSTM (one cooperative dispatch) ----------------
// Block bid owns j-quad = bid*4..bid*4+3 for BOTH layers. Super-step s:
//   layer-1: y1[s] from e[s] + h1 (slab s);  layer-2: out[s-1] from y1[s-1]
//   (= slab s, SAME loads) + h2 (slab s-1). 128 barriers total.
// Base = R0 (256 threads, hierarchical barrier; best measured 1486 us).
// THIS REV (isolated change: STORE-PATH COALESCING):
//  (1) h stores: wave shfl-gather -> lanes 0-15 store 8B packed (4 bf16 j
//      values per b-row) write-through. 256x2B -> 64x8B transactions/slab.
//      Old pattern was 64 scattered 2B lines per wave (32x amplification);
//      WRITE_SIZE=199MB vs ~67MB logical shows the RMW cost.
//  (2) outy: f32 scratch oscr[s][j][b] (block-private dense 64B lines, NO
//      cross-XCD false sharing; old direct store had 4 XCDs RMW-ing each
//      64B line) + post-pass transpose kernel. ws_size-guarded fallback.
// Consumer load layout [b][k] and the visibility protocol are unchanged.
__global__ __launch_bounds__(256, 1) void lstm_fused(
    const unsigned short* __restrict__ W1t,  // [4096][256]  bf16
    const unsigned short* __restrict__ U1t,  // [4096][1024] bf16
    const unsigned short* __restrict__ W2t,  // [4096][1024] bf16
    const unsigned short* __restrict__ U2t,  // [4096][1024] bf16
    const unsigned short* __restrict__ ebf,  // [8192][256]  bf16
    unsigned short* __restrict__ h1h,        // [129][64][1024], slab 0 prefilled
    unsigned short* __restrict__ h2h,        // [129][64][1024], slab 0 prefilled
    const float* __restrict__ c0_1, const float* __restrict__ c0_2,
    const float* __restrict__ b1,   const float* __restrict__ b2,
    float* __restrict__ outy,                 // [64][128][1024]
    float* __restrict__ oscr,                 // [128][1024][64] f32 scratch (if use_oscr)
    int use_oscr,
    float* __restrict__ hT1, float* __restrict__ cT1,
    float* __restrict__ hT2, float* __restrict__ cT2,
    unsigned int* __restrict__ bar) {
  extern __shared__ __align__(16) unsigned short lds[];   // 104 KB
  unsigned short* U1l = lds;             // 32 KB
  unsigned short* W2l = lds + 16384;     // 32 KB
  unsigned short* U2l = lds + 32768;     // 32 KB
  unsigned short* W1l = lds + 49152;     // 8 KB
  const int bid = blockIdx.x, tid = threadIdx.x;
  const int w = tid >> 6, l = tid & 63;

  // stage A-fragments from n-major bf16 arrays; each wave reads full 64B lines
  for (int run = tid; run < 2048; run += 256) {
    int ll = run & 63, ks = run >> 6;
    int m = ll & 15;
    int n = (m & 3) * 1024 + bid * 4 + (m >> 2);
    int kb = ks * 32 + (ll >> 4) * 8;
    *(short8*)&U1l[run * 8] = *(const short8*)&U1t[(size_t)n * 1024 + kb];
    *(short8*)&W2l[run * 8] = *(const short8*)&W2t[(size_t)n * 1024 + kb];
    *(short8*)&U2l[run * 8] = *(const short8*)&U2t[(size_t)n * 1024 + kb];
  }
  for (int run = tid; run < 512; run += 256) {
    int ll = run & 63, ks = run >> 6;
    int m = ll & 15;
    int n = (m & 3) * 1024 + bid * 4 + (m >> 2);
    int kb = ks * 32 + (ll >> 4) * 8;
    *(short8*)&W1l[run * 8] = *(const short8*)&W1t[(size_t)n * 256 + kb];
  }
  __syncthreads();

  const int b = w * 16 + (l & 15);
  const int jj = l >> 4;
  const int j = bid * 4 + jj;
  const int kq = jj * 8;
  float c1 = c0_1[b * 1024 + j];
  float c2 = c0_2[b * 1024 + j];
  float b1r[4], b2r[4];
#pragma unroll
  for (int g = 0; g < 4; ++g) { b1r[g] = b1[g * 1024 + j]; b2r[g] = b2[g * 1024 + j]; }

  // ---- s = 0: layer-1 only ----
  {
    const unsigned short* er = ebf + ((size_t)b << 8);        // t=0 row
    const unsigned short* h1row = h1h + (size_t)b * 1024;     // slab 0
    short8 ev[8], h1v[32];
#pragma unroll
    for (int k = 0; k < 8; ++k) ev[k] = *(const short8*)&er[k * 32 + kq];
#pragma unroll
    for (int ks = 0; ks < 32; ++ks) h1v[ks] = *(const short8*)&h1row[ks * 32 + kq];
    floatx4 a1a = {0.f, 0.f, 0.f, 0.f}, a1b = a1a;
#pragma unroll
    for (int k = 0; k < 8; ++k) {
      short8 w1 = *(const short8*)&W1l[(k * 64 + l) * 8];
      if (k & 1) a1b = MFMA16(w1, ev[k], a1b); else a1a = MFMA16(w1, ev[k], a1a);
    }
#pragma unroll
    for (int ks = 0; ks < 32; ++ks) {
      short8 u1 = *(const short8*)&U1l[(ks * 64 + l) * 8];
      if (ks & 1) a1b = MFMA16(u1, h1v[ks], a1b); else a1a = MFMA16(u1, h1v[ks], a1a);
    }
    floatx4 z1 = a1a + a1b;
    float ig = sigm(z1[0] + b1r[0]), fg = sigm(z1[1] + b1r[1]);
    float gg = tanh_f(z1[2] + b1r[2]), og = sigm(z1[3] + b1r[3]);
    c1 = fg * c1 + ig * gg;
    float h = og * tanh_f(c1);
    {
      unsigned int hb = (unsigned int)f2bf(h);
      int src = l & 15;
      unsigned int g0 = (unsigned int)__shfl((int)hb, src);
      unsigned int g1 = (unsigned int)__shfl((int)hb, src + 16);
      unsigned int g2 = (unsigned int)__shfl((int)hb, src + 32);
      unsigned int g3 = (unsigned int)__shfl((int)hb, src + 48);
      if (l < 16) {
        unsigned long long pk = (unsigned long long)(g0 & 0xffffu)
          | (((unsigned long long)(g1 & 0xffffu)) << 16)
          | (((unsigned long long)(g2 & 0xffffu)) << 32)
          | (((unsigned long long)(g3 & 0xffffu)) << 48);
        llc_store_u64(h1h + 65536 + (size_t)(w * 16 + l) * 1024 + (size_t)bid * 4, pk);
      }
    }
    gridbar(bar, 1u);
  }

  // ---- s = 1..127: both layers ----
  for (int s = 1; s < 128; ++s) {
    const unsigned short* er = ebf + ((size_t)(s * 64 + b) << 8);
    const unsigned short* h1row = h1h + (size_t)s * 65536 + (size_t)b * 1024;
    const unsigned short* h2row = h2h + (size_t)(s - 1) * 65536 + (size_t)b * 1024;
    // bulk prefetch: issue ALL global loads for this step back-to-back
    short8 ev[8], h1v[32], h2v[32];
#pragma unroll
    for (int ks = 0; ks < 32; ++ks) h1v[ks] = *(const short8*)&h1row[ks * 32 + kq];
#pragma unroll
    for (int ks = 0; ks < 32; ++ks) h2v[ks] = *(const short8*)&h2row[ks * 32 + kq];
#pragma unroll
    for (int k = 0; k < 8; ++k) ev[k] = *(const short8*)&er[k * 32 + kq];

    floatx4 a1a = {0.f, 0.f, 0.f, 0.f}, a1b = a1a;
    floatx4 a2a = a1a, a2b = a1a, a2c = a1a, a2d = a1a;
#pragma unroll
    for (int k = 0; k < 8; ++k) {
      short8 w1 = *(const short8*)&W1l[(k * 64 + l) * 8];
      if (k & 1) a1b = MFMA16(w1, ev[k], a1b); else a1a = MFMA16(w1, ev[k], a1a);
    }
#pragma unroll
    for (int ks = 0; ks < 32; ++ks) {
      short8 u1 = *(const short8*)&U1l[(ks * 64 + l) * 8];
      short8 w2 = *(const short8*)&W2l[(ks * 64 + l) * 8];
      short8 u2 = *(const short8*)&U2l[(ks * 64 + l) * 8];
      if (ks & 1) {
        a1b = MFMA16(u1, h1v[ks], a1b);
        a2b = MFMA16(w2, h1v[ks], a2b);
        a2d = MFMA16(u2, h2v[ks], a2d);
      } else {
        a1a = MFMA16(u1, h1v[ks], a1a);
        a2a = MFMA16(w2, h1v[ks], a2a);
        a2c = MFMA16(u2, h2v[ks], a2c);
      }
    }
    floatx4 z1 = a1a + a1b, z2 = (a2a + a2b) + (a2c + a2d);
    {
      float ig = sigm(z1[0] + b1r[0]), fg = sigm(z1[1] + b1r[1]);
      float gg = tanh_f(z1[2] + b1r[2]), og = sigm(z1[3] + b1r[3]);
      c1 = fg * c1 + ig * gg;
      float h = og * tanh_f(c1);
      unsigned int hb = (unsigned int)f2bf(h);
      int src = l & 15;
      unsigned int g0 = (unsigned int)__shfl((int)hb, src);
      unsigned int g1 = (unsigned int)__shfl((int)hb, src + 16);
      unsigned int g2 = (unsigned int)__shfl((int)hb, src + 32);
      unsigned int g3 = (unsigned int)__shfl((int)hb, src + 48);
      if (l < 16) {
        unsigned long long pk = (unsigned long long)(g0 & 0xffffu)
          | (((unsigned long long)(g1 & 0xffffu)) << 16)
          | (((unsigned long long)(g2 & 0xffffu)) << 32)
          | (((unsigned long long)(g3 & 0xffffu)) << 48);
        llc_store_u64(h1h + (size_t)(s + 1) * 65536 + (size_t)(w * 16 + l) * 1024 + (size_t)bid * 4, pk);
      }
      if (s == 127) { hT1[b * 1024 + j] = h; cT1[b * 1024 + j] = c1; }
    }
    {
      float ig = sigm(z2[0] + b2r[0]), fg = sigm(z2[1] + b2r[1]);
      float gg = tanh_f(z2[2] + b2r[2]), og = sigm(z2[3] + b2r[3]);
      c2 = fg * c2 + ig * gg;
      float h = og * tanh_f(c2);
      unsigned int hb = (unsigned int)f2bf(h);
      int src = l & 15;
      unsigned int g0 = (unsigned int)__shfl((int)hb, src);
      unsigned int g1 = (unsigned int)__shfl((int)hb, src + 16);
      unsigned int g2 = (unsigned int)__shfl((int)hb, src + 32);
      unsigned int g3 = (unsigned int)__shfl((int)hb, src + 48);
      if (l < 16) {
        unsigned long long pk = (unsigned long long)(g0 & 0xffffu)
          | (((unsigned long long)(g1 & 0xffffu)) << 16)
          | (((unsigned long long)(g2 & 0xffffu)) << 32)
          | (((unsigned long long)(g3 & 0xffffu)) << 48);
        llc_store_u64(h2h + (size_t)s * 65536 + (size_t)(w * 16 + l) * 1024 + (size_t)bid * 4, pk);
      }
      if (use_oscr) {
        oscr[(size_t)(s - 1) * 65536 + (size_t)(bid * 4 + jj) * 64 + b] = h;
      } else {
        outy[(size_t)b * 131072 + (size_t)(s - 1) * 1024 + j] = h;
      }
    }
    gridbar(bar, (unsigned int)(s + 1));
  }

  // ---- s = 128: layer-2 only ----
  {
    const unsigned short* h1row = h1h + (size_t)128 * 65536 + (size_t)b * 1024;
    const unsigned short* h2row = h2h + (size_t)127 * 65536 + (size_t)b * 1024;
    short8 h1v[32], h2v[32];
#pragma unroll
    for (int ks = 0; ks < 32; ++ks) h1v[ks] = *(const short8*)&h1row[ks * 32 + kq];
#pragma unroll
    for (int ks = 0; ks < 32; ++ks) h2v[ks] = *(const short8*)&h2row[ks * 32 + kq];
    floatx4 a2a = {0.f, 0.f, 0.f, 0.f}, a2b = a2a, a2c = a2a, a2d = a2a;
#pragma unroll
    for (int ks = 0; ks < 32; ++ks) {
      short8 w2 = *(const short8*)&W2l[(ks * 64 + l) * 8];
      short8 u2 = *(const short8*)&U2l[(ks * 64 + l) * 8];
      if (ks & 1) { a2b = MFMA16(w2, h1v[ks], a2b); a2d = MFMA16(u2, h2v[ks], a2d); }
      else        { a2a = MFMA16(w2, h1v[ks], a2a); a2c = MFMA16(u2, h2v[ks], a2c); }
    }
    floatx4 z2 = (a2a + a2b) + (a2c + a2d);
    float ig = sigm(z2[0] + b2r[0]), fg = sigm(z2[1] + b2r[1]);
    float gg = tanh_f(z2[2] + b2r[2]), og = sigm(z2[3] + b2r[3]);
    c2 = fg * c2 + ig * gg;
    float h = og * tanh_f(c2);
    if (use_oscr) {
      oscr[(size_t)127 * 65536 + (size_t)(bid * 4 + jj) * 64 + b] = h;
    } else {
      outy[(size_t)b * 131072 + (size_t)127 * 1024 + j] = h;
    }
    hT2[b * 1024 + j] = h;
    cT2[b * 1024 + j] = c2;
  }
}

// ---------------- launch ----------------
extern "C" void kernel_launch(void* const* d_in, const int* in_sizes, int n_in,
                              void* d_out, int out_size, void* d_ws, size_t ws_size,
                              hipStream_t stream) {
  const int*   x    = (const int*)d_in[0];
  const float* h0_1 = (const float*)d_in[1];
  const float* c0_1 = (const float*)d_in[2];
  const float* h0_2 = (const float*)d_in[3];
  const float* c0_2 = (const float*)d_in[4];
  const float* emb  = (const float*)d_in[5];
  const float* W1   = (const float*)d_in[6];
  const float* U1   = (const float*)d_in[7];
  const float* b1   = (const float*)d_in[8];
  const float* W2   = (const float*)d_in[9];
  const float* U2   = (const float*)d_in[10];
  const float* b2   = (const float*)d_in[11];
  float* outf = (float*)d_out;

  unsigned short* ws  = (unsigned short*)d_ws;
  unsigned short* ebf = ws;                    //  2,097,152 ush
  unsigned short* W1t = ws +  2097152;         //  1,048,576
  unsigned short* U1t = ws +  3145728;         //  4,194,304
  unsigned short* W2t = ws +  7340032;         //  4,194,304
  unsigned short* U2t = ws + 11534336;         //  4,194,304
  unsigned short* h1h = ws + 15728640;         //  8,454,144
  unsigned short* h2h = ws + 24182784;         //  8,454,144
  unsigned int*   bar = (unsigned int*)(ws + 32636928);  // 4 KB
  float*          oscr = (float*)(ws + 32638976);        // 33.5 MB f32 [128][1024][64]
  const size_t need_bytes = (size_t)32638976 * 2 + (size_t)33554432;
  const int use_oscr = (ws_size >= need_bytes) ? 1 : 0;

  float* hT1 = outf + 8388608;
  float* cT1 = outf + 8454144;
  float* hT2 = outf + 8519680;
  float* cT2 = outf + 8585216;

  zero_bar<<<4, 256, 0, stream>>>(bar);
  prep_e<<<1024, 256, 0, stream>>>(x, emb, ebf);
  prep_wt<<<512,  256, 0, stream>>>(W1, W1t, 256);
  prep_wt<<<2048, 256, 0, stream>>>(U1, U1t, 1024);
  prep_wt<<<2048, 256, 0, stream>>>(W2, W2t, 1024);
  prep_wt<<<2048, 256, 0, stream>>>(U2, U2t, 1024);
  prep_cvt<<<256, 256, 0, stream>>>(h0_1, h1h);
  prep_cvt<<<256, 256, 0, stream>>>(h0_2, h2h);

  // allow 104 KB dynamic LDS (gfx950 has 160 KB/CU)
  static bool attr_done = false;
  if (!attr_done) {
    (void)hipFuncSetAttribute((const void*)lstm_fused,
                              hipFuncAttributeMaxDynamicSharedMemorySize, 106496);
    attr_done = true;
  }

  {
    const unsigned short *w1c = W1t, *u1c = U1t, *w2c = W2t, *u2c = U2t, *ec = ebf;
    unsigned short *h1c = h1h, *h2c = h2h;
    const float *c01 = c0_1, *c02 = c0_2, *b1c = b1, *b2c = b2;
    float *oy = outf, *osc = oscr, *ht1 = hT1, *ct1 = cT1, *ht2 = hT2, *ct2 = cT2;
    int uo = use_oscr;
    unsigned int* brc = bar;
    void* args[] = {&w1c, &u1c, &w2c, &u2c, &ec, &h1c, &h2c,
                    &c01, &c02, &b1c, &b2c, &oy, &osc, &uo, &ht1, &ct1, &ht2, &ct2, &brc};
    hipError_t e = hipLaunchCooperativeKernel((void*)lstm_fused, dim3(256), dim3(256),
                                              args, 106496, stream);
    if (e != hipSuccess) {
      // Defensive fallback: 256 blocks x 104 KB LDS = 1 block/CU on 256 CUs,
      // so all blocks are co-resident under a plain launch too; the gridbar
      // remains safe.
      lstm_fused<<<dim3(256), dim3(256), 106496, stream>>>(
          w1c, u1c, w2c, u2c, ec, h1c, h2c, c01, c02, b1c, b2c,
          oy, osc, uo, ht1, ct1, ht2, ct2, brc);
    }
  }

  if (use_oscr) {
    out_tr<<<2048, 256, 0, stream>>>(oscr, outf);
  }
}

// Round 9
// 1151.025 us; speedup vs baseline: 1.7761x; 1.3474x over previous
//
#include <hip/hip_runtime.h>

typedef __attribute__((ext_vector_type(8))) short short8;
typedef __attribute__((ext_vector_type(4))) float floatx4;

#define MFMA16(a, b, acc) __builtin_amdgcn_mfma_f32_16x16x32_bf16((a), (b), (acc), 0, 0, 0)

__device__ __forceinline__ float bf2f(unsigned short u) {
  union { float f; unsigned int i; } v; v.i = ((unsigned int)u) << 16; return v.f;
}
__device__ __forceinline__ unsigned short f2bf(float f) {
  union { float f; unsigned int i; } v; v.f = f;
  unsigned int r = (v.i + 0x7fffu + ((v.i >> 16) & 1u)) >> 16;
  return (unsigned short)r;
}
__device__ __forceinline__ float sigm(float x) { return 1.0f / (1.0f + __expf(-x)); }
__device__ __forceinline__ float tanh_f(float x) { return 2.0f * sigm(2.0f * x) - 1.0f; }

// write-through 8B store: no L2 allocation, lands at LLC (coherence point)
__device__ __forceinline__ void llc_store_u64(unsigned short* p, unsigned long long v) {
  asm volatile("global_store_dwordx2 %0, %1, off sc0 sc1" :: "v"(p), "v"(v) : "memory");
}

// h slabs are BLOCK-MAJOR: h[s][q][b][r] where q = j>>2 (owning block), r = j&3.
// Producer block bid writes a contiguous 512B region per slab (full-line
// write-through). Reader: octet k=q0*4..q0*4+7 for batch b = two coalesced
// 8B loads from regions q0 and q0+1.
__device__ __forceinline__ short8 ld_h(const unsigned short* slab, int b, int q0) {
  union { short8 s; uint2 u[2]; } r;
  r.u[0] = *(const uint2*)(slab + q0 * 256 + b * 4);
  r.u[1] = *(const uint2*)(slab + (q0 + 1) * 256 + b * 4);
  return r.s;
}

// ---------------- hierarchical checker barrier (R0-proven, verbatim) ----------------
// R5/R6 established: flat-poll and counter variants are 2-3.5 us/step WORSE
// (poll flooding / arrival serialization). Keep this one.
__device__ __forceinline__ void gridbar(unsigned int* bar, unsigned int phase) {
  __syncthreads();                     // compiler emits vmcnt(0) drain before s_barrier
  const unsigned int bid = blockIdx.x;
  const unsigned int tid = threadIdx.x;
  unsigned int* flags  = bar;          // 256 dwords
  unsigned int* gflags = bar + 256;    // 8 dwords (line 16)
  unsigned int* gen    = bar + 512;    // line 32
  if (tid == 0)
    __hip_atomic_store(&flags[bid], phase, __ATOMIC_RELAXED, __HIP_MEMORY_SCOPE_AGENT);
  asm volatile("" ::: "memory");
  if ((bid & 31u) == 0u && tid < 64) {         // leader wave
    const unsigned int g = bid >> 5;
    unsigned int v;
    do {
      v = __hip_atomic_load(&flags[g * 32 + (tid & 31)], __ATOMIC_RELAXED, __HIP_MEMORY_SCOPE_AGENT);
      if (v < phase) __builtin_amdgcn_s_sleep(1);
    } while (__all(v >= phase) == 0);
    if (tid == 0)
      __hip_atomic_store(&gflags[g], phase, __ATOMIC_RELAXED, __HIP_MEMORY_SCOPE_AGENT);
    if (bid == 0) {                            // root
      unsigned int gv;
      do {
        gv = __hip_atomic_load(&gflags[tid & 7], __ATOMIC_RELAXED, __HIP_MEMORY_SCOPE_AGENT);
        if (gv < phase) __builtin_amdgcn_s_sleep(1);
      } while (__all(gv >= phase) == 0);
      if (tid == 0)
        __hip_atomic_store(gen, phase, __ATOMIC_RELAXED, __HIP_MEMORY_SCOPE_AGENT);
    }
  }
  if (tid == 0) {
    while (__hip_atomic_load(gen, __ATOMIC_RELAXED, __HIP_MEMORY_SCOPE_AGENT) < phase)
      __builtin_amdgcn_s_sleep(1);
  }
  asm volatile("" ::: "memory");       // no load hoisting above the poll
  __syncthreads();
}

__global__ void zero_bar(unsigned int* bar) {
  int i = blockIdx.x * 256 + threadIdx.x;
  if (i < 1024) bar[i] = 0u;
}

// ---------------- prep kernels ----------------

// ebf[m=t*64+b][k] = bf16(emb[x[b][t]][k])
__global__ void prep_e(const int* __restrict__ x, const float* __restrict__ emb,
                       unsigned short* __restrict__ ebf) {
  int idx = blockIdx.x * 256 + threadIdx.x;   // [0, 8192*32)
  int koct = idx & 31;
  int m = idx >> 5;
  int t = m >> 6, b = m & 63;
  int tok = x[b * 128 + t];
  const float* src = emb + (size_t)tok * 256 + (size_t)koct * 8;
  short8 v;
#pragma unroll
  for (int j = 0; j < 8; ++j) v[j] = (short)f2bf(src[j]);
  *(short8*)(ebf + (size_t)m * 256 + koct * 8) = v;
}

// Wt[n][k] = bf16(W[k][n]); W is [K][4096]
__global__ void prep_wt(const float* __restrict__ W, unsigned short* __restrict__ Wt, int K) {
  int idx = blockIdx.x * 256 + threadIdx.x;   // [0, 4096*(K/8))
  int n = idx & 4095;
  int koct = idx >> 12;
  short8 v;
#pragma unroll
  for (int j = 0; j < 8; ++j) v[j] = (short)f2bf(W[(size_t)(koct * 8 + j) * 4096 + n]);
  *(short8*)(Wt + (size_t)n * K + koct * 8) = v;
}

// h0 prefill into BLOCK-MAJOR layout: d[(j>>2)*256 + b*4 + (j&3)] = bf16(s[b][j])
__global__ void prep_cvt_h(const float* __restrict__ s, unsigned short* __restrict__ d) {
  int i = blockIdx.x * 256 + threadIdx.x;     // [0, 65536)
  int b = i >> 10, j = i & 1023;
  d[(j >> 2) * 256 + b * 4 + (j & 3)] = f2bf(s[i]);
}

// out transpose: outy[b][s][j] = oscr[s][j][b]   (both f32, fully coalesced)
__global__ __launch_bounds__(256) void out_tr(const float* __restrict__ oscr,
                                              float* __restrict__ outy) {
  __shared__ float t[64][65];
  const int s = blockIdx.x & 127, jc = blockIdx.x >> 7;   // grid 2048 = 128 s x 16 jc
  const int tid = threadIdx.x;
  const int r0 = tid >> 6, cc = tid & 63;
#pragma unroll
  for (int r = 0; r < 16; ++r) {
    int jr = r * 4 + r0;
    t[jr][cc] = oscr[(size_t)s * 65536 + (size_t)(jc * 64 + jr) * 64 + cc];
  }
  __syncthreads();
#pragma unroll
  for (int r = 0; r < 16; ++r) {
    int br = r * 4 + r0;
    outy[(size_t)br * 131072 + (size_t)s * 1024 + jc * 64 + cc] = t[cc][br];
  }
}

// ---------------- fused two-layer LSTM (one cooperative dispatch) ----------------
// Block bid owns j-quad = bid*4..bid*4+3 for BOTH layers. Super-step s:
//   layer-1: y1[s] from e[s] + h1 (slab s);  layer-2: out[s-1] from y1[s-1]
//   (= slab s, SAME loads) + h2 (slab s-1). 128 barriers total.
// Base = R8 (store-coalesced, 1374 us measured).
// THIS REV (isolated change: BLOCK-MAJOR h LAYOUT -> FULL-LINE h STORES):
//   h[s][j>>2][b][j&3]. Producer wave: shfl-pack + 16 lanes x 8B CONTIGUOUS
//   = 2 full 64B lines write-through (R8's [b][j] layout left each 64B line
//   split across 8 blocks -> ~4x transaction amplification; WRITE_SIZE 166MB
//   vs ~66MB logical). Reader: 2 coalesced dwordx2 per octet (same bytes,
//   2x VMEM instr). Math bit-identical; sync untouched.
__global__ __launch_bounds__(256, 1) void lstm_fused(
    const unsigned short* __restrict__ W1t,  // [4096][256]  bf16
    const unsigned short* __restrict__ U1t,  // [4096][1024] bf16
    const unsigned short* __restrict__ W2t,  // [4096][1024] bf16
    const unsigned short* __restrict__ U2t,  // [4096][1024] bf16
    const unsigned short* __restrict__ ebf,  // [8192][256]  bf16
    unsigned short* __restrict__ h1h,        // [129][256][64][4] block-major, slab 0 prefilled
    unsigned short* __restrict__ h2h,        // [129][256][64][4] block-major, slab 0 prefilled
    const float* __restrict__ c0_1, const float* __restrict__ c0_2,
    const float* __restrict__ b1,   const float* __restrict__ b2,
    float* __restrict__ outy,                 // [64][128][1024]
    float* __restrict__ oscr,                 // [128][1024][64] f32 scratch (if use_oscr)
    int use_oscr,
    float* __restrict__ hT1, float* __restrict__ cT1,
    float* __restrict__ hT2, float* __restrict__ cT2,
    unsigned int* __restrict__ bar) {
  extern __shared__ __align__(16) unsigned short lds[];   // 104 KB
  unsigned short* U1l = lds;             // 32 KB
  unsigned short* W2l = lds + 16384;     // 32 KB
  unsigned short* U2l = lds + 32768;     // 32 KB
  unsigned short* W1l = lds + 49152;     // 8 KB
  const int bid = blockIdx.x, tid = threadIdx.x;
  const int w = tid >> 6, l = tid & 63;

  // stage A-fragments from n-major bf16 arrays; each wave reads full 64B lines
  for (int run = tid; run < 2048; run += 256) {
    int ll = run & 63, ks = run >> 6;
    int m = ll & 15;
    int n = (m & 3) * 1024 + bid * 4 + (m >> 2);
    int kb = ks * 32 + (ll >> 4) * 8;
    *(short8*)&U1l[run * 8] = *(const short8*)&U1t[(size_t)n * 1024 + kb];
    *(short8*)&W2l[run * 8] = *(const short8*)&W2t[(size_t)n * 1024 + kb];
    *(short8*)&U2l[run * 8] = *(const short8*)&U2t[(size_t)n * 1024 + kb];
  }
  for (int run = tid; run < 512; run += 256) {
    int ll = run & 63, ks = run >> 6;
    int m = ll & 15;
    int n = (m & 3) * 1024 + bid * 4 + (m >> 2);
    int kb = ks * 32 + (ll >> 4) * 8;
    *(short8*)&W1l[run * 8] = *(const short8*)&W1t[(size_t)n * 256 + kb];
  }
  __syncthreads();

  const int b = w * 16 + (l & 15);
  const int jj = l >> 4;
  const int j = bid * 4 + jj;
  const int kq = jj * 8;
  const int q2 = jj * 2;                 // octet q0 base: ks*8 + jj*2
  float c1 = c0_1[b * 1024 + j];
  float c2 = c0_2[b * 1024 + j];
  float b1r[4], b2r[4];
#pragma unroll
  for (int g = 0; g < 4; ++g) { b1r[g] = b1[g * 1024 + j]; b2r[g] = b2[g * 1024 + j]; }

  // ---- s = 0: layer-1 only ----
  {
    const unsigned short* er = ebf + ((size_t)b << 8);        // t=0 row
    const unsigned short* h1sl = h1h;                         // slab 0
    short8 ev[8], h1v[32];
#pragma unroll
    for (int k = 0; k < 8; ++k) ev[k] = *(const short8*)&er[k * 32 + kq];
#pragma unroll
    for (int ks = 0; ks < 32; ++ks) h1v[ks] = ld_h(h1sl, b, ks * 8 + q2);
    floatx4 a1a = {0.f, 0.f, 0.f, 0.f}, a1b = a1a;
#pragma unroll
    for (int k = 0; k < 8; ++k) {
      short8 w1 = *(const short8*)&W1l[(k * 64 + l) * 8];
      if (k & 1) a1b = MFMA16(w1, ev[k], a1b); else a1a = MFMA16(w1, ev[k], a1a);
    }
#pragma unroll
    for (int ks = 0; ks < 32; ++ks) {
      short8 u1 = *(const short8*)&U1l[(ks * 64 + l) * 8];
      if (ks & 1) a1b = MFMA16(u1, h1v[ks], a1b); else a1a = MFMA16(u1, h1v[ks], a1a);
    }
    floatx4 z1 = a1a + a1b;
    float ig = sigm(z1[0] + b1r[0]), fg = sigm(z1[1] + b1r[1]);
    float gg = tanh_f(z1[2] + b1r[2]), og = sigm(z1[3] + b1r[3]);
    c1 = fg * c1 + ig * gg;
    float h = og * tanh_f(c1);
    {
      unsigned int hb = (unsigned int)f2bf(h);
      int src = l & 15;
      unsigned int g0 = (unsigned int)__shfl((int)hb, src);
      unsigned int g1 = (unsigned int)__shfl((int)hb, src + 16);
      unsigned int g2 = (unsigned int)__shfl((int)hb, src + 32);
      unsigned int g3 = (unsigned int)__shfl((int)hb, src + 48);
      if (l < 16) {
        unsigned long long pk = (unsigned long long)(g0 & 0xffffu)
          | (((unsigned long long)(g1 & 0xffffu)) << 16)
          | (((unsigned long long)(g2 & 0xffffu)) << 32)
          | (((unsigned long long)(g3 & 0xffffu)) << 48);
        // block-major: slab 1, region bid, row b = w*16+l  -> contiguous 128B/wave
        llc_store_u64(h1h + (size_t)65536 + bid * 256 + (w * 16 + l) * 4, pk);
      }
    }
    gridbar(bar, 1u);
  }

  // ---- s = 1..127: both layers ----
  for (int s = 1; s < 128; ++s) {
    const unsigned short* er = ebf + ((size_t)(s * 64 + b) << 8);
    const unsigned short* h1sl = h1h + (size_t)s * 65536;
    const unsigned short* h2sl = h2h + (size_t)(s - 1) * 65536;
    // bulk prefetch: issue ALL global loads for this step back-to-back
    short8 ev[8], h1v[32], h2v[32];
#pragma unroll
    for (int ks = 0; ks < 32; ++ks) h1v[ks] = ld_h(h1sl, b, ks * 8 + q2);
#pragma unroll
    for (int ks = 0; ks < 32; ++ks) h2v[ks] = ld_h(h2sl, b, ks * 8 + q2);
#pragma unroll
    for (int k = 0; k < 8; ++k) ev[k] = *(const short8*)&er[k * 32 + kq];

    floatx4 a1a = {0.f, 0.f, 0.f, 0.f}, a1b = a1a;
    floatx4 a2a = a1a, a2b = a1a, a2c = a1a, a2d = a1a;
#pragma unroll
    for (int k = 0; k < 8; ++k) {
      short8 w1 = *(const short8*)&W1l[(k * 64 + l) * 8];
      if (k & 1) a1b = MFMA16(w1, ev[k], a1b); else a1a = MFMA16(w1, ev[k], a1a);
    }
#pragma unroll
    for (int ks = 0; ks < 32; ++ks) {
      short8 u1 = *(const short8*)&U1l[(ks * 64 + l) * 8];
      short8 w2 = *(const short8*)&W2l[(ks * 64 + l) * 8];
      short8 u2 = *(const short8*)&U2l[(ks * 64 + l) * 8];
      if (ks & 1) {
        a1b = MFMA16(u1, h1v[ks], a1b);
        a2b = MFMA16(w2, h1v[ks], a2b);
        a2d = MFMA16(u2, h2v[ks], a2d);
      } else {
        a1a = MFMA16(u1, h1v[ks], a1a);
        a2a = MFMA16(w2, h1v[ks], a2a);
        a2c = MFMA16(u2, h2v[ks], a2c);
      }
    }
    floatx4 z1 = a1a + a1b, z2 = (a2a + a2b) + (a2c + a2d);
    {
      float ig = sigm(z1[0] + b1r[0]), fg = sigm(z1[1] + b1r[1]);
      float gg = tanh_f(z1[2] + b1r[2]), og = sigm(z1[3] + b1r[3]);
      c1 = fg * c1 + ig * gg;
      float h = og * tanh_f(c1);
      unsigned int hb = (unsigned int)f2bf(h);
      int src = l & 15;
      unsigned int g0 = (unsigned int)__shfl((int)hb, src);
      unsigned int g1 = (unsigned int)__shfl((int)hb, src + 16);
      unsigned int g2 = (unsigned int)__shfl((int)hb, src + 32);
      unsigned int g3 = (unsigned int)__shfl((int)hb, src + 48);
      if (l < 16) {
        unsigned long long pk = (unsigned long long)(g0 & 0xffffu)
          | (((unsigned long long)(g1 & 0xffffu)) << 16)
          | (((unsigned long long)(g2 & 0xffffu)) << 32)
          | (((unsigned long long)(g3 & 0xffffu)) << 48);
        llc_store_u64(h1h + (size_t)(s + 1) * 65536 + bid * 256 + (w * 16 + l) * 4, pk);
      }
      if (s == 127) { hT1[b * 1024 + j] = h; cT1[b * 1024 + j] = c1; }
    }
    {
      float ig = sigm(z2[0] + b2r[0]), fg = sigm(z2[1] + b2r[1]);
      float gg = tanh_f(z2[2] + b2r[2]), og = sigm(z2[3] + b2r[3]);
      c2 = fg * c2 + ig * gg;
      float h = og * tanh_f(c2);
      unsigned int hb = (unsigned int)f2bf(h);
      int src = l & 15;
      unsigned int g0 = (unsigned int)__shfl((int)hb, src);
      unsigned int g1 = (unsigned int)__shfl((int)hb, src + 16);
      unsigned int g2 = (unsigned int)__shfl((int)hb, src + 32);
      unsigned int g3 = (unsigned int)__shfl((int)hb, src + 48);
      if (l < 16) {
        unsigned long long pk = (unsigned long long)(g0 & 0xffffu)
          | (((unsigned long long)(g1 & 0xffffu)) << 16)
          | (((unsigned long long)(g2 & 0xffffu)) << 32)
          | (((unsigned long long)(g3 & 0xffffu)) << 48);
        llc_store_u64(h2h + (size_t)s * 65536 + bid * 256 + (w * 16 + l) * 4, pk);
      }
      if (use_oscr) {
        oscr[(size_t)(s - 1) * 65536 + (size_t)(bid * 4 + jj) * 64 + b] = h;
      } else {
        outy[(size_t)b * 131072 + (size_t)(s - 1) * 1024 + j] = h;
      }
    }
    gridbar(bar, (unsigned int)(s + 1));
  }

  // ---- s = 128: layer-2 only ----
  {
    const unsigned short* h1sl = h1h + (size_t)128 * 65536;
    const unsigned short* h2sl = h2h + (size_t)127 * 65536;
    short8 h1v[32], h2v[32];
#pragma unroll
    for (int ks = 0; ks < 32; ++ks) h1v[ks] = ld_h(h1sl, b, ks * 8 + q2);
#pragma unroll
    for (int ks = 0; ks < 32; ++ks) h2v[ks] = ld_h(h2sl, b, ks * 8 + q2);
    floatx4 a2a = {0.f, 0.f, 0.f, 0.f}, a2b = a2a, a2c = a2a, a2d = a2a;
#pragma unroll
    for (int ks = 0; ks < 32; ++ks) {
      short8 w2 = *(const short8*)&W2l[(ks * 64 + l) * 8];
      short8 u2 = *(const short8*)&U2l[(ks * 64 + l) * 8];
      if (ks & 1) { a2b = MFMA16(w2, h1v[ks], a2b); a2d = MFMA16(u2, h2v[ks], a2d); }
      else        { a2a = MFMA16(w2, h1v[ks], a2a); a2c = MFMA16(u2, h2v[ks], a2c); }
    }
    floatx4 z2 = (a2a + a2b) + (a2c + a2d);
    float ig = sigm(z2[0] + b2r[0]), fg = sigm(z2[1] + b2r[1]);
    float gg = tanh_f(z2[2] + b2r[2]), og = sigm(z2[3] + b2r[3]);
    c2 = fg * c2 + ig * gg;
    float h = og * tanh_f(c2);
    if (use_oscr) {
      oscr[(size_t)127 * 65536 + (size_t)(bid * 4 + jj) * 64 + b] = h;
    } else {
      outy[(size_t)b * 131072 + (size_t)127 * 1024 + j] = h;
    }
    hT2[b * 1024 + j] = h;
    cT2[b * 1024 + j] = c2;
  }
}

// ---------------- launch ----------------
extern "C" void kernel_launch(void* const* d_in, const int* in_sizes, int n_in,
                              void* d_out, int out_size, void* d_ws, size_t ws_size,
                              hipStream_t stream) {
  const int*   x    = (const int*)d_in[0];
  const float* h0_1 = (const float*)d_in[1];
  const float* c0_1 = (const float*)d_in[2];
  const float* h0_2 = (const float*)d_in[3];
  const float* c0_2 = (const float*)d_in[4];
  const float* emb  = (const float*)d_in[5];
  const float* W1   = (const float*)d_in[6];
  const float* U1   = (const float*)d_in[7];
  const float* b1   = (const float*)d_in[8];
  const float* W2   = (const float*)d_in[9];
  const float* U2   = (const float*)d_in[10];
  const float* b2   = (const float*)d_in[11];
  float* outf = (float*)d_out;

  unsigned short* ws  = (unsigned short*)d_ws;
  unsigned short* ebf = ws;                    //  2,097,152 ush
  unsigned short* W1t = ws +  2097152;         //  1,048,576
  unsigned short* U1t = ws +  3145728;         //  4,194,304
  unsigned short* W2t = ws +  7340032;         //  4,194,304
  unsigned short* U2t = ws + 11534336;         //  4,194,304
  unsigned short* h1h = ws + 15728640;         //  8,454,144  (block-major slabs)
  unsigned short* h2h = ws + 24182784;         //  8,454,144  (block-major slabs)
  unsigned int*   bar = (unsigned int*)(ws + 32636928);  // 4 KB
  float*          oscr = (float*)(ws + 32638976);        // 33.5 MB f32 [128][1024][64]
  const size_t need_bytes = (size_t)32638976 * 2 + (size_t)33554432;
  const int use_oscr = (ws_size >= need_bytes) ? 1 : 0;

  float* hT1 = outf + 8388608;
  float* cT1 = outf + 8454144;
  float* hT2 = outf + 8519680;
  float* cT2 = outf + 8585216;

  zero_bar<<<4, 256, 0, stream>>>(bar);
  prep_e<<<1024, 256, 0, stream>>>(x, emb, ebf);
  prep_wt<<<512,  256, 0, stream>>>(W1, W1t, 256);
  prep_wt<<<2048, 256, 0, stream>>>(U1, U1t, 1024);
  prep_wt<<<2048, 256, 0, stream>>>(W2, W2t, 1024);
  prep_wt<<<2048, 256, 0, stream>>>(U2, U2t, 1024);
  prep_cvt_h<<<256, 256, 0, stream>>>(h0_1, h1h);
  prep_cvt_h<<<256, 256, 0, stream>>>(h0_2, h2h);

  // allow 104 KB dynamic LDS (gfx950 has 160 KB/CU)
  static bool attr_done = false;
  if (!attr_done) {
    (void)hipFuncSetAttribute((const void*)lstm_fused,
                              hipFuncAttributeMaxDynamicSharedMemorySize, 106496);
    attr_done = true;
  }

  {
    const unsigned short *w1c = W1t, *u1c = U1t, *w2c = W2t, *u2c = U2t, *ec = ebf;
    unsigned short *h1c = h1h, *h2c = h2h;
    const float *c01 = c0_1, *c02 = c0_2, *b1c = b1, *b2c = b2;
    float *oy = outf, *osc = oscr, *ht1 = hT1, *ct1 = cT1, *ht2 = hT2, *ct2 = cT2;
    int uo = use_oscr;
    unsigned int* brc = bar;
    void* args[] = {&w1c, &u1c, &w2c, &u2c, &ec, &h1c, &h2c,
                    &c01, &c02, &b1c, &b2c, &oy, &osc, &uo, &ht1, &ct1, &ht2, &ct2, &brc};
    hipError_t e = hipLaunchCooperativeKernel((void*)lstm_fused, dim3(256), dim3(256),
                                              args, 106496, stream);
    if (e != hipSuccess) {
      // Defensive fallback: 256 blocks x 104 KB LDS = 1 block/CU on 256 CUs,
      // so all blocks are co-resident under a plain launch too; the gridbar
      // remains safe.
      lstm_fused<<<dim3(256), dim3(256), 106496, stream>>>(
          w1c, u1c, w2c, u2c, ec, h1c, h2c, c01, c02, b1c, b2c,
          oy, osc, uo, ht1, ct1, ht2, ct2, brc);
    }
  }

  if (use_oscr) {
    out_tr<<<2048, 256, 0, stream>>>(oscr, outf);
  }
}